// Round 6
// baseline (898.971 us; speedup 1.0000x reference)
//
#include <hip/hip_runtime.h>
#include <hip/hip_bf16.h>
#include <hip/hip_fp16.h>
#include <math.h>

#define N_ATOMS 5000
#define N_EDGES 100000
#define F 128
#define B 20
#define NL 3
#define CAP 96

constexpr float CUTOFF = 5.0f;
constexpr float PI_F = 3.14159265358979323846f;

__device__ __forceinline__ float silu_f(float x) { return x / (1.0f + __expf(-x)); }

// ---------------------------------------------------------------- init: s = emb[Z]
__global__ void init_kernel(const int* __restrict__ Z, const float* __restrict__ emb,
                            float* __restrict__ s) {
    int atom = blockIdx.x;
    int t = threadIdx.x;
    s[atom * F + t] = emb[Z[atom] * F + t];
}

// ---------------------------------------------------------------- bucket edges by dst
__global__ void fill_buckets(const int* __restrict__ eidx, int* __restrict__ count,
                             int* __restrict__ bucket) {
    int e = blockIdx.x * 256 + threadIdx.x;
    if (e >= N_EDGES) return;
    int dst = eidx[2 * e];
    int pos = atomicAdd(&count[dst], 1);
    if (pos < CAP) bucket[dst * CAP + pos] = e;
}

// ---------------------------------------------------------------- transpose all weights
struct TPlan { const float* src; float* dst; int R, C, blk0; };
struct TPlans { TPlan p[20]; int n; };

__global__ void transpose_all(TPlans P) {
    int b = blockIdx.x;
    int pi = 0;
#pragma unroll
    for (int i = 1; i < 20; ++i)
        if (i < P.n && b >= P.p[i].blk0) pi = i;
    const float* src = P.p[pi].src;
    float* dst = P.p[pi].dst;
    int R = P.p[pi].R, C = P.p[pi].C;
    int f = (b - P.p[pi].blk0) * 256 + threadIdx.x;
    if (f < R * C) {
        int c = f / R, r = f - c * R;
        dst[f] = src[r * C + c];
    }
}

// ---------------------------------------------------------------- phi = silu(s@W1+b1)@W2+b2
// 384 threads = 3 teams of 128; TA=4 atoms/block -> 1250 blocks (29 waves/CU offered).
// Stage 1: team g computes hidden-layer partial over its k-range.
// Stage 2: thread (g,t) computes output column o = g*128+t for all 4 atoms.
__global__ __launch_bounds__(384) void phi_kernel(
    const float* __restrict__ s, const float* __restrict__ w1T, const float* __restrict__ b1,
    const float* __restrict__ w2T, const float* __restrict__ b2, __half* __restrict__ phi_h) {
    __shared__ __align__(16) float sh_s[F][4];
    __shared__ __align__(16) float sh_p[3][F][4];
    __shared__ __align__(16) float sh_h[F][4];
    int a0 = blockIdx.x * 4;
    int tid = threadIdx.x;
    int t = tid & 127, g = tid >> 7;
    if (g == 0) {
#pragma unroll
        for (int a = 0; a < 4; ++a) sh_s[t][a] = s[(a0 + a) * F + t];
    }
    __syncthreads();

    // stage 1: k-split thirds (float4-aligned boundaries)
    int kstart = (g == 0) ? 0 : (g == 1 ? 44 : 88);
    int kend   = (g == 0) ? 44 : (g == 1 ? 88 : 128);
    float p0 = 0.f, p1 = 0.f, p2 = 0.f, p3 = 0.f;
    const float* wrow = w1T + t * F;
    for (int k = kstart; k < kend; k += 4) {
        float4 wq = *(const float4*)(wrow + k);
        float4 x0 = *(const float4*)&sh_s[k][0];
        float4 x1 = *(const float4*)&sh_s[k + 1][0];
        float4 x2 = *(const float4*)&sh_s[k + 2][0];
        float4 x3 = *(const float4*)&sh_s[k + 3][0];
        p0 += x0.x * wq.x + x1.x * wq.y + x2.x * wq.z + x3.x * wq.w;
        p1 += x0.y * wq.x + x1.y * wq.y + x2.y * wq.z + x3.y * wq.w;
        p2 += x0.z * wq.x + x1.z * wq.y + x2.z * wq.z + x3.z * wq.w;
        p3 += x0.w * wq.x + x1.w * wq.y + x2.w * wq.z + x3.w * wq.w;
    }
    sh_p[g][t][0] = p0; sh_p[g][t][1] = p1; sh_p[g][t][2] = p2; sh_p[g][t][3] = p3;
    __syncthreads();
    if (g == 0) {
        float bb = b1[t];
#pragma unroll
        for (int a = 0; a < 4; ++a)
            sh_h[t][a] = silu_f(bb + sh_p[0][t][a] + sh_p[1][t][a] + sh_p[2][t][a]);
    }
    __syncthreads();

    // stage 2
    int o = g * 128 + t;
    float bo = b2[o];
    float A0 = bo, A1 = bo, A2 = bo, A3 = bo;
    const float* r = w2T + o * F;
#pragma unroll 4
    for (int k = 0; k < F; k += 4) {
        float4 wq = *(const float4*)(r + k);
        float4 x0 = *(const float4*)&sh_h[k][0];
        float4 x1 = *(const float4*)&sh_h[k + 1][0];
        float4 x2 = *(const float4*)&sh_h[k + 2][0];
        float4 x3 = *(const float4*)&sh_h[k + 3][0];
        A0 += x0.x * wq.x + x1.x * wq.y + x2.x * wq.z + x3.x * wq.w;
        A1 += x0.y * wq.x + x1.y * wq.y + x2.y * wq.z + x3.y * wq.w;
        A2 += x0.z * wq.x + x1.z * wq.y + x2.z * wq.z + x3.z * wq.w;
        A3 += x0.w * wq.x + x1.w * wq.y + x2.w * wq.z + x3.w * wq.w;
    }
    phi_h[(size_t)(a0 + 0) * 3 * F + o] = __float2half(A0);
    phi_h[(size_t)(a0 + 1) * 3 * F + o] = __float2half(A1);
    phi_h[(size_t)(a0 + 2) * 3 * F + o] = __float2half(A2);
    phi_h[(size_t)(a0 + 3) * 3 * F + o] = __float2half(A3);
}

// ---------------------------------------------------------------- per-dst edge aggregation
// fp16 gathers of phi/v, software-pipelined groups of 4 edges (round-5, kept)
__global__ __launch_bounds__(128) void edge_agg_kernel(
    const int* __restrict__ count, const int* __restrict__ bucket,
    const int* __restrict__ eidx, const float* __restrict__ ediff,
    const float* __restrict__ edist,
    const float* __restrict__ fw, const float* __restrict__ fb,
    const __half* __restrict__ phi_h, const __half* __restrict__ v_h,
    float* __restrict__ ds, float* __restrict__ dv) {
    int a = blockIdx.x;
    int t = threadIdx.x;

    float rfw0[B], rfw1[B], rfw2[B];
#pragma unroll
    for (int b = 0; b < B; ++b) {
        const float* row = fw + b * 3 * F;
        rfw0[b] = row[t]; rfw1[b] = row[F + t]; rfw2[b] = row[2 * F + t];
    }
    float fb0 = fb[t], fb1 = fb[F + t], fb2 = fb[2 * F + t];

    int n = count[a]; if (n > CAP) n = CAP;
    float accS = 0.f, accV0 = 0.f, accV1 = 0.f, accV2 = 0.f;

    __shared__ __align__(16) float sh_rbf[32][B];
    __shared__ float sh_env[32];
    __shared__ float sh_unit[32][3];
    __shared__ int sh_src[32];
    const int* bptr = bucket + a * CAP;

    for (int base = 0; base < n; base += 32) {
        int cnt = min(32, n - base);
        __syncthreads();
        if (t < cnt) {
            int e = bptr[base + t];
            sh_src[t] = eidx[2 * e + 1];
            float d = edist[e];
            float fc = 0.5f * (cosf(PI_F * d / CUTOFF) + 1.0f);
            sh_env[t] = (d < CUTOFF) ? fc : 0.0f;
            float inv = 1.0f / d;
            sh_unit[t][0] = ediff[3 * e + 0] * inv;
            sh_unit[t][1] = ediff[3 * e + 1] * inv;
            sh_unit[t][2] = ediff[3 * e + 2] * inv;
        }
        for (int task = t; task < cnt * B; task += 128) {
            int i = task / B, b = task - i * B;
            int e = bptr[base + i];
            float d = edist[e];
            sh_rbf[i][b] = sinf(d * (float)(b + 1) * (PI_F / CUTOFF)) / d;
        }
        __syncthreads();

        __half PA[4][3], VA[4][3], PB[4][3], VB[4][3];
        int ngrp = (cnt + 3) >> 2;

        auto load_grp = [&](int gbase, __half P[4][3], __half V4[4][3]) {
#pragma unroll
            for (int j = 0; j < 4; ++j) {
                int i = gbase + j;
                int ii = (i < cnt) ? i : (cnt - 1);
                int src = sh_src[ii];
                const __half* ps = phi_h + (size_t)src * 3 * F;
                const __half* vs = v_h + (size_t)src * 3 * F;
                P[j][0] = ps[t]; P[j][1] = ps[F + t]; P[j][2] = ps[2 * F + t];
                V4[j][0] = vs[t]; V4[j][1] = vs[F + t]; V4[j][2] = vs[2 * F + t];
            }
        };
        auto comp_grp = [&](int gbase, __half P[4][3], __half V4[4][3]) {
#pragma unroll
            for (int j = 0; j < 4; ++j) {
                int i = gbase + j;
                if (i < cnt) {
                    float f0 = fb0, f1 = fb1, f2 = fb2;
#pragma unroll
                    for (int b = 0; b < B; ++b) {
                        float r = sh_rbf[i][b];
                        f0 += r * rfw0[b]; f1 += r * rfw1[b]; f2 += r * rfw2[b];
                    }
                    float env = sh_env[i];
                    f0 *= env; f1 *= env; f2 *= env;
                    accS += f2 * __half2float(P[j][2]);
                    float gsv = f0 * __half2float(P[j][0]);
                    float gev = f1 * __half2float(P[j][1]);
                    accV0 += __half2float(V4[j][0]) * gsv + gev * sh_unit[i][0];
                    accV1 += __half2float(V4[j][1]) * gsv + gev * sh_unit[i][1];
                    accV2 += __half2float(V4[j][2]) * gsv + gev * sh_unit[i][2];
                }
            }
        };

        load_grp(0, PA, VA);
        for (int g = 0; g < ngrp; g += 2) {
            if (g + 1 < ngrp) load_grp((g + 1) * 4, PB, VB);
            comp_grp(g * 4, PA, VA);
            if (g + 1 < ngrp) {
                if (g + 2 < ngrp) load_grp((g + 2) * 4, PA, VA);
                comp_grp((g + 1) * 4, PB, VB);
            }
        }
    }
    ds[a * F + t] = accS;
    float* dvd = dv + a * 3 * F;
    dvd[t] = accV0; dvd[F + t] = accV1; dvd[2 * F + t] = accV2;
}

// ---------------------------------------------------------------- per-atom update
// 384 threads = 3 teams; TA=4 atoms/block -> 1250 blocks.
// Stage A: team g owns spatial dim d=g (Uv,Vv); norm/dot partials via LDS.
// Stage B: team 0 = s-part, team 1 = vn-part of the a-MLP hidden layer.
// Stage C: thread (g,t) computes a-MLP output column o=g*128+t.
__global__ __launch_bounds__(384) void update_kernel(
    float* __restrict__ s, float* __restrict__ v, __half* __restrict__ v_h,
    const float* __restrict__ ds, const float* __restrict__ dv,
    const float* __restrict__ UT, const float* __restrict__ VT,
    const float* __restrict__ w1T, const float* __restrict__ b1,
    const float* __restrict__ w2T, const float* __restrict__ b2) {
    __shared__ __align__(16) float sh_s[F][4];
    __shared__ __align__(16) float sh_v[3][F][4];
    __shared__ __align__(16) float sh_vn[F][4];
    __shared__ __align__(16) float sh_h[F][4];
    __shared__ __align__(16) float sh_aux[3][F][4];   // sq -> mlp1 partials -> stage-C outputs
    __shared__ __align__(16) float sh_dot[3][F][4];
    int a0 = blockIdx.x * 4;
    int tid = threadIdx.x;
    int t = tid & 127, g = tid >> 7;
#pragma unroll
    for (int a = 0; a < 4; ++a) {
        int atom = a0 + a;
        sh_v[g][t][a] = v[atom * 3 * F + g * F + t] + dv[atom * 3 * F + g * F + t];
    }
    if (g == 0) {
#pragma unroll
        for (int a = 0; a < 4; ++a) {
            int atom = a0 + a;
            sh_s[t][a] = s[atom * F + t] + ds[atom * F + t];
        }
    }
    __syncthreads();

    // stage A: Uv/Vv for d = g
    float uv0 = 0.f, uv1 = 0.f, uv2 = 0.f, uv3 = 0.f;
    float vv0 = 0.f, vv1 = 0.f, vv2 = 0.f, vv3 = 0.f;
    const float* ur = UT + t * F;
    const float* vr = VT + t * F;
#pragma unroll 4
    for (int k = 0; k < F; k += 4) {
        float4 uq = *(const float4*)(ur + k);
        float4 vq = *(const float4*)(vr + k);
        float4 x0 = *(const float4*)&sh_v[g][k][0];
        float4 x1 = *(const float4*)&sh_v[g][k + 1][0];
        float4 x2 = *(const float4*)&sh_v[g][k + 2][0];
        float4 x3 = *(const float4*)&sh_v[g][k + 3][0];
        uv0 += x0.x * uq.x + x1.x * uq.y + x2.x * uq.z + x3.x * uq.w;
        uv1 += x0.y * uq.x + x1.y * uq.y + x2.y * uq.z + x3.y * uq.w;
        uv2 += x0.z * uq.x + x1.z * uq.y + x2.z * uq.z + x3.z * uq.w;
        uv3 += x0.w * uq.x + x1.w * uq.y + x2.w * uq.z + x3.w * uq.w;
        vv0 += x0.x * vq.x + x1.x * vq.y + x2.x * vq.z + x3.x * vq.w;
        vv1 += x0.y * vq.x + x1.y * vq.y + x2.y * vq.z + x3.y * vq.w;
        vv2 += x0.z * vq.x + x1.z * vq.y + x2.z * vq.z + x3.z * vq.w;
        vv3 += x0.w * vq.x + x1.w * vq.y + x2.w * vq.z + x3.w * vq.w;
    }
    sh_aux[g][t][0] = vv0 * vv0; sh_aux[g][t][1] = vv1 * vv1;
    sh_aux[g][t][2] = vv2 * vv2; sh_aux[g][t][3] = vv3 * vv3;
    sh_dot[g][t][0] = uv0 * vv0; sh_dot[g][t][1] = uv1 * vv1;
    sh_dot[g][t][2] = uv2 * vv2; sh_dot[g][t][3] = uv3 * vv3;
    __syncthreads();
    if (g == 0) {
#pragma unroll
        for (int a = 0; a < 4; ++a)
            sh_vn[t][a] = sqrtf(sh_aux[0][t][a] + sh_aux[1][t][a] + sh_aux[2][t][a]);
    }
    __syncthreads();

    // stage B: a-MLP hidden layer; team 0 -> s half, team 1 -> vn half
    if (g < 2) {
        float h0 = 0.f, h1 = 0.f, h2 = 0.f, h3 = 0.f;
        const float* ar = w1T + t * 2 * F + g * F;
        const float (*src)[4] = (g == 0) ? sh_s : sh_vn;
#pragma unroll 4
        for (int k = 0; k < F; k += 4) {
            float4 wq = *(const float4*)(ar + k);
            float4 x0 = *(const float4*)&src[k][0];
            float4 x1 = *(const float4*)&src[k + 1][0];
            float4 x2 = *(const float4*)&src[k + 2][0];
            float4 x3 = *(const float4*)&src[k + 3][0];
            h0 += x0.x * wq.x + x1.x * wq.y + x2.x * wq.z + x3.x * wq.w;
            h1 += x0.y * wq.x + x1.y * wq.y + x2.y * wq.z + x3.y * wq.w;
            h2 += x0.z * wq.x + x1.z * wq.y + x2.z * wq.z + x3.z * wq.w;
            h3 += x0.w * wq.x + x1.w * wq.y + x2.w * wq.z + x3.w * wq.w;
        }
        sh_aux[g][t][0] = h0; sh_aux[g][t][1] = h1;
        sh_aux[g][t][2] = h2; sh_aux[g][t][3] = h3;
    }
    __syncthreads();
    if (g == 0) {
        float bb = b1[t];
#pragma unroll
        for (int a = 0; a < 4; ++a)
            sh_h[t][a] = silu_f(bb + sh_aux[0][t][a] + sh_aux[1][t][a]);
    }
    __syncthreads();

    // stage C: output column o
    int o = g * 128 + t;
    float bo = b2[o];
    float A0 = bo, A1 = bo, A2 = bo, A3 = bo;
    const float* r = w2T + o * F;
#pragma unroll 4
    for (int k = 0; k < F; k += 4) {
        float4 wq = *(const float4*)(r + k);
        float4 x0 = *(const float4*)&sh_h[k][0];
        float4 x1 = *(const float4*)&sh_h[k + 1][0];
        float4 x2 = *(const float4*)&sh_h[k + 2][0];
        float4 x3 = *(const float4*)&sh_h[k + 3][0];
        A0 += x0.x * wq.x + x1.x * wq.y + x2.x * wq.z + x3.x * wq.w;
        A1 += x0.y * wq.x + x1.y * wq.y + x2.y * wq.z + x3.y * wq.w;
        A2 += x0.z * wq.x + x1.z * wq.y + x2.z * wq.z + x3.z * wq.w;
        A3 += x0.w * wq.x + x1.w * wq.y + x2.w * wq.z + x3.w * wq.w;
    }
    sh_aux[g][t][0] = A0; sh_aux[g][t][1] = A1;
    sh_aux[g][t][2] = A2; sh_aux[g][t][3] = A3;
    __syncthreads();

    // final: avv = aux[0], asv = aux[1], ass = aux[2]
    float uvr[4] = {uv0, uv1, uv2, uv3};
#pragma unroll
    for (int a = 0; a < 4; ++a) {
        int atom = a0 + a;
        float avv = sh_aux[0][t][a];
        float nv = sh_v[g][t][a] + avv * uvr[a];
        v[atom * 3 * F + g * F + t] = nv;
        v_h[(size_t)atom * 3 * F + g * F + t] = __float2half(nv);
        if (g == 0) {
            float dot = sh_dot[0][t][a] + sh_dot[1][t][a] + sh_dot[2][t][a];
            s[atom * F + t] = sh_s[t][a] + sh_aux[1][t][a] * dot + sh_aux[2][t][a];
        }
    }
}

// ---------------------------------------------------------------- readout, 16 atoms/block, 64 threads
__global__ __launch_bounds__(64) void readout_kernel(
    const float* __restrict__ s, const float* __restrict__ w1T,
    const float* __restrict__ b1,
    const float* __restrict__ w2, const float* __restrict__ b2, float* __restrict__ out) {
    const int TA = 16;
    __shared__ __align__(16) float sh_s[F][20];
    int a0 = blockIdx.x * TA;
    int t = threadIdx.x;
#pragma unroll
    for (int a = 0; a < TA; ++a) {
        int atom = a0 + a;
        sh_s[t][a]      = (atom < N_ATOMS) ? s[atom * F + t] : 0.0f;
        sh_s[t + 64][a] = (atom < N_ATOMS) ? s[atom * F + 64 + t] : 0.0f;
    }
    __syncthreads();
    float acc[TA];
    float bb = b1[t];
#pragma unroll
    for (int a = 0; a < TA; ++a) acc[a] = bb;
    const float* wr = w1T + t * F;
#pragma unroll 2
    for (int k = 0; k < F; k += 4) {
        float4 wq = *(const float4*)(wr + k);
        float wj[4] = {wq.x, wq.y, wq.z, wq.w};
#pragma unroll
        for (int j = 0; j < 4; ++j) {
            const float* rp = &sh_s[k + j][0];
            float4 q0 = *(const float4*)(rp), q1 = *(const float4*)(rp + 4);
            float4 q2 = *(const float4*)(rp + 8), q3 = *(const float4*)(rp + 12);
            float sv[TA] = {q0.x, q0.y, q0.z, q0.w, q1.x, q1.y, q1.z, q1.w,
                            q2.x, q2.y, q2.z, q2.w, q3.x, q3.y, q3.z, q3.w};
#pragma unroll
            for (int a = 0; a < TA; ++a) acc[a] += sv[a] * wj[j];
        }
    }
    float w2t = w2[t];
    float p[TA];
#pragma unroll
    for (int a = 0; a < TA; ++a) p[a] = silu_f(acc[a]) * w2t;
#pragma unroll
    for (int a = 0; a < TA; ++a)
#pragma unroll
        for (int off = 32; off > 0; off >>= 1) p[a] += __shfl_down(p[a], off, 64);
    if (t == 0) {
        float bias = b2[0];
#pragma unroll
        for (int a = 0; a < TA; ++a) {
            int atom = a0 + a;
            if (atom < N_ATOMS) out[atom] = p[a] + bias;
        }
    }
}

extern "C" void kernel_launch(void* const* d_in, const int* in_sizes, int n_in,
                              void* d_out, int out_size, void* d_ws, size_t ws_size,
                              hipStream_t stream) {
    const int*   Z      = (const int*)d_in[0];
    const int*   eidx   = (const int*)d_in[1];
    const float* ediff  = (const float*)d_in[2];
    const float* edist  = (const float*)d_in[3];
    const float* emb    = (const float*)d_in[4];
    const float* msg_w1 = (const float*)d_in[5];
    const float* msg_b1 = (const float*)d_in[6];
    const float* msg_w2 = (const float*)d_in[7];
    const float* msg_b2 = (const float*)d_in[8];
    const float* filt_w = (const float*)d_in[9];
    const float* filt_b = (const float*)d_in[10];
    const float* upd_U  = (const float*)d_in[11];
    const float* upd_V  = (const float*)d_in[12];
    const float* upd_w1 = (const float*)d_in[13];
    const float* upd_b1 = (const float*)d_in[14];
    const float* upd_w2 = (const float*)d_in[15];
    const float* upd_b2 = (const float*)d_in[16];
    const float* ro_w1  = (const float*)d_in[17];
    const float* ro_b1  = (const float*)d_in[18];
    const float* ro_w2  = (const float*)d_in[19];
    const float* ro_b2  = (const float*)d_in[20];
    float* out = (float*)d_out;

    float* ws  = (float*)d_ws;
    float* s    = ws;                     // N*F fp32
    float* v    = s + N_ATOMS * F;        // N*3F fp32
    float* ds   = v + N_ATOMS * 3 * F;    // N*F fp32
    float* dv   = ds + N_ATOMS * F;       // N*3F fp32
    int* count  = (int*)(dv + N_ATOMS * 3 * F);  // N
    int* bucket = count + N_ATOMS;               // N*CAP
    float* wT   = (float*)(bucket + N_ATOMS * CAP);

    const int L_W1T = F * F, L_W2T = F * 3 * F, L_UT = F * F, L_VT = F * F,
              L_UW1T = 2 * F * F, L_UW2T = F * 3 * F;
    const int LAYER_T = L_W1T + L_W2T + L_UT + L_VT + L_UW1T + L_UW2T;
    float* w1T_base  = wT;
    float* w2T_base  = wT + L_W1T;
    float* UT_base   = wT + L_W1T + L_W2T;
    float* VT_base   = wT + L_W1T + L_W2T + L_UT;
    float* uw1T_base = wT + L_W1T + L_W2T + L_UT + L_VT;
    float* uw2T_base = wT + L_W1T + L_W2T + L_UT + L_VT + L_UW1T;
    float* roT       = wT + (size_t)NL * LAYER_T;   // [64][F]
    __half* phi_h = (__half*)(roT + F * 64);            // N*3F half
    __half* v_h   = phi_h + (size_t)N_ATOMS * 3 * F;    // N*3F half

    TPlans P;
    int nb = 0, pi = 0;
    auto add = [&](const float* src, float* dst, int R, int C) {
        P.p[pi].src = src; P.p[pi].dst = dst; P.p[pi].R = R; P.p[pi].C = C;
        P.p[pi].blk0 = nb;
        nb += (R * C + 255) / 256; ++pi;
    };
    for (int l = 0; l < NL; ++l) {
        add(msg_w1 + l * F * F,     w1T_base  + l * LAYER_T, F, F);
        add(msg_w2 + l * F * 3 * F, w2T_base  + l * LAYER_T, F, 3 * F);
        add(upd_U  + l * F * F,     UT_base   + l * LAYER_T, F, F);
        add(upd_V  + l * F * F,     VT_base   + l * LAYER_T, F, F);
        add(upd_w1 + l * 2 * F * F, uw1T_base + l * LAYER_T, 2 * F, F);
        add(upd_w2 + l * F * 3 * F, uw2T_base + l * LAYER_T, F, 3 * F);
    }
    add(ro_w1, roT, F, 64);
    P.n = pi;

    init_kernel<<<N_ATOMS, F, 0, stream>>>(Z, emb, s);
    hipMemsetAsync(v, 0, (size_t)N_ATOMS * 3 * F * sizeof(float), stream);
    hipMemsetAsync(v_h, 0, (size_t)N_ATOMS * 3 * F * sizeof(__half), stream);
    hipMemsetAsync(count, 0, (size_t)N_ATOMS * sizeof(int), stream);
    fill_buckets<<<(N_EDGES + 255) / 256, 256, 0, stream>>>(eidx, count, bucket);
    transpose_all<<<nb, 256, 0, stream>>>(P);

    for (int l = 0; l < NL; ++l) {
        phi_kernel<<<N_ATOMS / 4, 384, 0, stream>>>(
            s, w1T_base + l * LAYER_T, msg_b1 + l * F,
            w2T_base + l * LAYER_T, msg_b2 + l * 3 * F, phi_h);
        edge_agg_kernel<<<N_ATOMS, 128, 0, stream>>>(
            count, bucket, eidx, ediff, edist,
            filt_w + l * B * 3 * F, filt_b + l * 3 * F, phi_h, v_h, ds, dv);
        update_kernel<<<N_ATOMS / 4, 384, 0, stream>>>(
            s, v, v_h, ds, dv, UT_base + l * LAYER_T, VT_base + l * LAYER_T,
            uw1T_base + l * LAYER_T, upd_b1 + l * F,
            uw2T_base + l * LAYER_T, upd_b2 + l * 3 * F);
    }
    readout_kernel<<<(N_ATOMS + 15) / 16, 64, 0, stream>>>(s, roT, ro_b1, ro_w2, ro_b2, out);
}

// Round 7
// 578.748 us; speedup vs baseline: 1.5533x; 1.5533x over previous
//
#include <hip/hip_runtime.h>
#include <hip/hip_bf16.h>
#include <hip/hip_fp16.h>
#include <math.h>

#define N_ATOMS 5000
#define N_EDGES 100000
#define F 128
#define B 20
#define NL 3
#define CAP 96

constexpr float CUTOFF = 5.0f;
constexpr float PI_F = 3.14159265358979323846f;

__device__ __forceinline__ float silu_f(float x) { return x / (1.0f + __expf(-x)); }

// ---------------------------------------------------------------- init: s = emb[Z]
__global__ void init_kernel(const int* __restrict__ Z, const float* __restrict__ emb,
                            float* __restrict__ s) {
    int atom = blockIdx.x;
    int t = threadIdx.x;
    s[atom * F + t] = emb[Z[atom] * F + t];
}

// ---------------------------------------------------------------- bucket edges by dst
__global__ void fill_buckets(const int* __restrict__ eidx, int* __restrict__ count,
                             int* __restrict__ bucket) {
    int e = blockIdx.x * 256 + threadIdx.x;
    if (e >= N_EDGES) return;
    int dst = eidx[2 * e];
    int pos = atomicAdd(&count[dst], 1);
    if (pos < CAP) bucket[dst * CAP + pos] = e;
}

// ---------------------------------------------------------------- transpose all weights
struct TPlan { const float* src; float* dst; int R, C, blk0; };
struct TPlans { TPlan p[20]; int n; };

__global__ void transpose_all(TPlans P) {
    int b = blockIdx.x;
    int pi = 0;
#pragma unroll
    for (int i = 1; i < 20; ++i)
        if (i < P.n && b >= P.p[i].blk0) pi = i;
    const float* src = P.p[pi].src;
    float* dst = P.p[pi].dst;
    int R = P.p[pi].R, C = P.p[pi].C;
    int f = (b - P.p[pi].blk0) * 256 + threadIdx.x;
    if (f < R * C) {
        int c = f / R, r = f - c * R;
        dst[f] = src[r * C + c];
    }
}

// ---------------------------------------------------------------- phi = silu(s@W1+b1)@W2+b2
// round-4/5 structure: 128 threads, 8 atoms/block, float4 transposed-weight loads
__global__ __launch_bounds__(128) void phi_kernel(
    const float* __restrict__ s, const float* __restrict__ w1T, const float* __restrict__ b1,
    const float* __restrict__ w2T, const float* __restrict__ b2, __half* __restrict__ phi_h) {
    __shared__ __align__(16) float sh_s[F][12];
    __shared__ __align__(16) float sh_h[F][12];
    int a0 = blockIdx.x * 8;
    int t = threadIdx.x;
#pragma unroll
    for (int a = 0; a < 8; ++a) sh_s[t][a] = s[(a0 + a) * F + t];
    __syncthreads();

    float acc[8];
    float bb = b1[t];
#pragma unroll
    for (int a = 0; a < 8; ++a) acc[a] = bb;
    const float* wrow = w1T + t * F;
#pragma unroll 4
    for (int k = 0; k < F; k += 4) {
        float4 wq = *(const float4*)(wrow + k);
        float wj[4] = {wq.x, wq.y, wq.z, wq.w};
#pragma unroll
        for (int j = 0; j < 4; ++j) {
            const float* rp = &sh_s[k + j][0];
            float4 q0 = *(const float4*)rp, q1 = *(const float4*)(rp + 4);
            float sv[8] = {q0.x, q0.y, q0.z, q0.w, q1.x, q1.y, q1.z, q1.w};
#pragma unroll
            for (int a = 0; a < 8; ++a) acc[a] += sv[a] * wj[j];
        }
    }
#pragma unroll
    for (int a = 0; a < 8; ++a) sh_h[t][a] = silu_f(acc[a]);
    __syncthreads();

    float A0[8], A1[8], A2[8];
    float c0 = b2[t], c1 = b2[F + t], c2 = b2[2 * F + t];
#pragma unroll
    for (int a = 0; a < 8; ++a) { A0[a] = c0; A1[a] = c1; A2[a] = c2; }
    const float* r0 = w2T + t * F;
    const float* r1 = w2T + (F + t) * F;
    const float* r2 = w2T + (2 * F + t) * F;
#pragma unroll 4
    for (int k = 0; k < F; k += 4) {
        float4 q0v = *(const float4*)(r0 + k);
        float4 q1v = *(const float4*)(r1 + k);
        float4 q2v = *(const float4*)(r2 + k);
        float w0j[4] = {q0v.x, q0v.y, q0v.z, q0v.w};
        float w1j[4] = {q1v.x, q1v.y, q1v.z, q1v.w};
        float w2j[4] = {q2v.x, q2v.y, q2v.z, q2v.w};
#pragma unroll
        for (int j = 0; j < 4; ++j) {
            const float* rp = &sh_h[k + j][0];
            float4 q0 = *(const float4*)rp, q1 = *(const float4*)(rp + 4);
            float hv[8] = {q0.x, q0.y, q0.z, q0.w, q1.x, q1.y, q1.z, q1.w};
#pragma unroll
            for (int a = 0; a < 8; ++a) {
                A0[a] += hv[a] * w0j[j]; A1[a] += hv[a] * w1j[j]; A2[a] += hv[a] * w2j[j];
            }
        }
    }
#pragma unroll
    for (int a = 0; a < 8; ++a) {
        __half* po = phi_h + (size_t)(a0 + a) * 3 * F;
        po[t] = __float2half(A0[a]);
        po[F + t] = __float2half(A1[a]);
        po[2 * F + t] = __float2half(A2[a]);
    }
}

// ---------------------------------------------------------------- per-dst edge aggregation
// 256 threads = 2 edge-teams x 128 feature-threads. Chunk staging is block-cooperative;
// teams process interleaved (even/odd) edges -> serial gather chain halved, no gather
// duplication. Partials combined via LDS.
__global__ __launch_bounds__(256) void edge_agg_kernel(
    const int* __restrict__ count, const int* __restrict__ bucket,
    const int* __restrict__ eidx, const float* __restrict__ ediff,
    const float* __restrict__ edist,
    const float* __restrict__ fw, const float* __restrict__ fb,
    const __half* __restrict__ phi_h, const __half* __restrict__ v_h,
    float* __restrict__ ds, float* __restrict__ dv) {
    int a = blockIdx.x;
    int tid = threadIdx.x;
    int t = tid & 127;
    int team = tid >> 7;   // 0..1

    float rfw0[B], rfw1[B], rfw2[B];
#pragma unroll
    for (int b = 0; b < B; ++b) {
        const float* row = fw + b * 3 * F;
        rfw0[b] = row[t]; rfw1[b] = row[F + t]; rfw2[b] = row[2 * F + t];
    }
    float fb0 = fb[t], fb1 = fb[F + t], fb2 = fb[2 * F + t];

    int n = count[a]; if (n > CAP) n = CAP;
    float accS = 0.f, accV0 = 0.f, accV1 = 0.f, accV2 = 0.f;

    __shared__ __align__(16) float sh_rbf[32][B];
    __shared__ float sh_env[32];
    __shared__ float sh_unit[32][3];
    __shared__ int sh_src[32];
    __shared__ __align__(16) float sh_part[4][F];
    const int* bptr = bucket + a * CAP;

    for (int base = 0; base < n; base += 32) {
        int cnt = min(32, n - base);
        __syncthreads();
        if (tid < cnt) {
            int e = bptr[base + tid];
            sh_src[tid] = eidx[2 * e + 1];
            float d = edist[e];
            float fc = 0.5f * (cosf(PI_F * d / CUTOFF) + 1.0f);
            sh_env[tid] = (d < CUTOFF) ? fc : 0.0f;
            float inv = 1.0f / d;
            sh_unit[tid][0] = ediff[3 * e + 0] * inv;
            sh_unit[tid][1] = ediff[3 * e + 1] * inv;
            sh_unit[tid][2] = ediff[3 * e + 2] * inv;
        }
        for (int task = tid; task < cnt * B; task += 256) {
            int i = task / B, b = task - i * B;
            int e = bptr[base + i];
            float d = edist[e];
            sh_rbf[i][b] = sinf(d * (float)(b + 1) * (PI_F / CUTOFF)) / d;
        }
        __syncthreads();

        // this team's edges within the chunk: ei = team + 2*i, i in [0, myCnt)
        int myCnt = (cnt > team) ? ((cnt - team + 1) >> 1) : 0;
        if (myCnt > 0) {
            __half PA[4][3], VA[4][3], PB[4][3], VB[4][3];
            int ngrp = (myCnt + 3) >> 2;

            auto load_grp = [&](int gbase, __half P[4][3], __half V4[4][3]) {
#pragma unroll
                for (int j = 0; j < 4; ++j) {
                    int i = gbase + j;
                    int ii = (i < myCnt) ? i : (myCnt - 1);
                    int src = sh_src[team + 2 * ii];
                    const __half* ps = phi_h + (size_t)src * 3 * F;
                    const __half* vs = v_h + (size_t)src * 3 * F;
                    P[j][0] = ps[t]; P[j][1] = ps[F + t]; P[j][2] = ps[2 * F + t];
                    V4[j][0] = vs[t]; V4[j][1] = vs[F + t]; V4[j][2] = vs[2 * F + t];
                }
            };
            auto comp_grp = [&](int gbase, __half P[4][3], __half V4[4][3]) {
#pragma unroll
                for (int j = 0; j < 4; ++j) {
                    int i = gbase + j;
                    if (i < myCnt) {
                        int ei = team + 2 * i;
                        float f0 = fb0, f1 = fb1, f2 = fb2;
#pragma unroll
                        for (int b = 0; b < B; ++b) {
                            float r = sh_rbf[ei][b];
                            f0 += r * rfw0[b]; f1 += r * rfw1[b]; f2 += r * rfw2[b];
                        }
                        float env = sh_env[ei];
                        f0 *= env; f1 *= env; f2 *= env;
                        accS += f2 * __half2float(P[j][2]);
                        float gsv = f0 * __half2float(P[j][0]);
                        float gev = f1 * __half2float(P[j][1]);
                        accV0 += __half2float(V4[j][0]) * gsv + gev * sh_unit[ei][0];
                        accV1 += __half2float(V4[j][1]) * gsv + gev * sh_unit[ei][1];
                        accV2 += __half2float(V4[j][2]) * gsv + gev * sh_unit[ei][2];
                    }
                }
            };

            load_grp(0, PA, VA);
            for (int g = 0; g < ngrp; g += 2) {
                if (g + 1 < ngrp) load_grp((g + 1) * 4, PB, VB);
                comp_grp(g * 4, PA, VA);
                if (g + 1 < ngrp) {
                    if (g + 2 < ngrp) load_grp((g + 2) * 4, PA, VA);
                    comp_grp((g + 1) * 4, PB, VB);
                }
            }
        }
    }

    __syncthreads();
    if (team == 1) {
        sh_part[0][t] = accS; sh_part[1][t] = accV0;
        sh_part[2][t] = accV1; sh_part[3][t] = accV2;
    }
    __syncthreads();
    if (team == 0) {
        ds[a * F + t] = accS + sh_part[0][t];
        float* dvd = dv + a * 3 * F;
        dvd[t] = accV0 + sh_part[1][t];
        dvd[F + t] = accV1 + sh_part[2][t];
        dvd[2 * F + t] = accV2 + sh_part[3][t];
    }
}

// ---------------------------------------------------------------- per-atom update
// round-4/5 structure: 128 threads, 8 atoms/block; writes fp32 v AND half shadow v_h
__global__ __launch_bounds__(128) void update_kernel(
    float* __restrict__ s, float* __restrict__ v, __half* __restrict__ v_h,
    const float* __restrict__ ds, const float* __restrict__ dv,
    const float* __restrict__ UT, const float* __restrict__ VT,
    const float* __restrict__ w1T, const float* __restrict__ b1,
    const float* __restrict__ w2T, const float* __restrict__ b2) {
    __shared__ __align__(16) float sh_s[F][12];
    __shared__ __align__(16) float sh_vn[F][12];
    __shared__ __align__(16) float sh_h[F][12];
    __shared__ __align__(16) float sh_v[3][F][12];
    int a0 = blockIdx.x * 8;
    int t = threadIdx.x;
    float sn[8];
#pragma unroll
    for (int a = 0; a < 8; ++a) {
        int atom = a0 + a;
        sn[a] = s[atom * F + t] + ds[atom * F + t];
        sh_s[t][a] = sn[a];
#pragma unroll
        for (int d = 0; d < 3; ++d)
            sh_v[d][t][a] = v[atom * 3 * F + d * F + t] + dv[atom * 3 * F + d * F + t];
    }
    __syncthreads();

    float uv[3][8], vv[3][8];
#pragma unroll
    for (int d = 0; d < 3; ++d)
#pragma unroll
        for (int a = 0; a < 8; ++a) { uv[d][a] = 0.f; vv[d][a] = 0.f; }
    const float* ur = UT + t * F;
    const float* vr = VT + t * F;
#pragma unroll 2
    for (int k = 0; k < F; k += 4) {
        float4 uq = *(const float4*)(ur + k);
        float4 vq = *(const float4*)(vr + k);
        float uj[4] = {uq.x, uq.y, uq.z, uq.w};
        float vj[4] = {vq.x, vq.y, vq.z, vq.w};
#pragma unroll
        for (int j = 0; j < 4; ++j) {
#pragma unroll
            for (int d = 0; d < 3; ++d) {
                const float* rp = &sh_v[d][k + j][0];
                float4 q0 = *(const float4*)rp, q1 = *(const float4*)(rp + 4);
                float xv[8] = {q0.x, q0.y, q0.z, q0.w, q1.x, q1.y, q1.z, q1.w};
#pragma unroll
                for (int a = 0; a < 8; ++a) {
                    uv[d][a] += xv[a] * uj[j]; vv[d][a] += xv[a] * vj[j];
                }
            }
        }
    }
#pragma unroll
    for (int a = 0; a < 8; ++a)
        sh_vn[t][a] = sqrtf(vv[0][a] * vv[0][a] + vv[1][a] * vv[1][a] + vv[2][a] * vv[2][a]);
    __syncthreads();

    float hh[8];
    float bb = b1[t];
#pragma unroll
    for (int a = 0; a < 8; ++a) hh[a] = bb;
    const float* ar = w1T + t * 2 * F;
#pragma unroll 2
    for (int k = 0; k < F; k += 4) {
        float4 wa = *(const float4*)(ar + k);
        float4 wb = *(const float4*)(ar + F + k);
        float waj[4] = {wa.x, wa.y, wa.z, wa.w};
        float wbj[4] = {wb.x, wb.y, wb.z, wb.w};
#pragma unroll
        for (int j = 0; j < 4; ++j) {
            const float* rs = &sh_s[k + j][0];
            const float* rn = &sh_vn[k + j][0];
            float4 s0 = *(const float4*)rs, s1 = *(const float4*)(rs + 4);
            float4 n0 = *(const float4*)rn, n1 = *(const float4*)(rn + 4);
            float svv[8] = {s0.x, s0.y, s0.z, s0.w, s1.x, s1.y, s1.z, s1.w};
            float nvv[8] = {n0.x, n0.y, n0.z, n0.w, n1.x, n1.y, n1.z, n1.w};
#pragma unroll
            for (int a = 0; a < 8; ++a) hh[a] += svv[a] * waj[j] + nvv[a] * wbj[j];
        }
    }
#pragma unroll
    for (int a = 0; a < 8; ++a) sh_h[t][a] = silu_f(hh[a]);
    __syncthreads();

    float A0[8], A1[8], A2[8];
    float c0 = b2[t], c1 = b2[F + t], c2 = b2[2 * F + t];
#pragma unroll
    for (int a = 0; a < 8; ++a) { A0[a] = c0; A1[a] = c1; A2[a] = c2; }
    const float* r0 = w2T + t * F;
    const float* r1 = w2T + (F + t) * F;
    const float* r2 = w2T + (2 * F + t) * F;
#pragma unroll 2
    for (int k = 0; k < F; k += 4) {
        float4 q0v = *(const float4*)(r0 + k);
        float4 q1v = *(const float4*)(r1 + k);
        float4 q2v = *(const float4*)(r2 + k);
        float w0j[4] = {q0v.x, q0v.y, q0v.z, q0v.w};
        float w1j[4] = {q1v.x, q1v.y, q1v.z, q1v.w};
        float w2j[4] = {q2v.x, q2v.y, q2v.z, q2v.w};
#pragma unroll
        for (int j = 0; j < 4; ++j) {
            const float* rp = &sh_h[k + j][0];
            float4 q0 = *(const float4*)rp, q1 = *(const float4*)(rp + 4);
            float hv[8] = {q0.x, q0.y, q0.z, q0.w, q1.x, q1.y, q1.z, q1.w};
#pragma unroll
            for (int a = 0; a < 8; ++a) {
                A0[a] += hv[a] * w0j[j]; A1[a] += hv[a] * w1j[j]; A2[a] += hv[a] * w2j[j];
            }
        }
    }
#pragma unroll
    for (int a = 0; a < 8; ++a) {
        int atom = a0 + a;
        float dot = uv[0][a] * vv[0][a] + uv[1][a] * vv[1][a] + uv[2][a] * vv[2][a];
#pragma unroll
        for (int d = 0; d < 3; ++d) {
            float nv = sh_v[d][t][a] + A0[a] * uv[d][a];
            v[atom * 3 * F + d * F + t] = nv;
            v_h[(size_t)atom * 3 * F + d * F + t] = __float2half(nv);
        }
        s[atom * F + t] = sn[a] + A1[a] * dot + A2[a];
    }
}

// ---------------------------------------------------------------- readout, 16 atoms/block, 64 threads
__global__ __launch_bounds__(64) void readout_kernel(
    const float* __restrict__ s, const float* __restrict__ w1T,
    const float* __restrict__ b1,
    const float* __restrict__ w2, const float* __restrict__ b2, float* __restrict__ out) {
    const int TA = 16;
    __shared__ __align__(16) float sh_s[F][20];
    int a0 = blockIdx.x * TA;
    int t = threadIdx.x;
#pragma unroll
    for (int a = 0; a < TA; ++a) {
        int atom = a0 + a;
        sh_s[t][a]      = (atom < N_ATOMS) ? s[atom * F + t] : 0.0f;
        sh_s[t + 64][a] = (atom < N_ATOMS) ? s[atom * F + 64 + t] : 0.0f;
    }
    __syncthreads();
    float acc[TA];
    float bb = b1[t];
#pragma unroll
    for (int a = 0; a < TA; ++a) acc[a] = bb;
    const float* wr = w1T + t * F;
#pragma unroll 2
    for (int k = 0; k < F; k += 4) {
        float4 wq = *(const float4*)(wr + k);
        float wj[4] = {wq.x, wq.y, wq.z, wq.w};
#pragma unroll
        for (int j = 0; j < 4; ++j) {
            const float* rp = &sh_s[k + j][0];
            float4 q0 = *(const float4*)(rp), q1 = *(const float4*)(rp + 4);
            float4 q2 = *(const float4*)(rp + 8), q3 = *(const float4*)(rp + 12);
            float sv[TA] = {q0.x, q0.y, q0.z, q0.w, q1.x, q1.y, q1.z, q1.w,
                            q2.x, q2.y, q2.z, q2.w, q3.x, q3.y, q3.z, q3.w};
#pragma unroll
            for (int a = 0; a < TA; ++a) acc[a] += sv[a] * wj[j];
        }
    }
    float w2t = w2[t];
    float p[TA];
#pragma unroll
    for (int a = 0; a < TA; ++a) p[a] = silu_f(acc[a]) * w2t;
#pragma unroll
    for (int a = 0; a < TA; ++a)
#pragma unroll
        for (int off = 32; off > 0; off >>= 1) p[a] += __shfl_down(p[a], off, 64);
    if (t == 0) {
        float bias = b2[0];
#pragma unroll
        for (int a = 0; a < TA; ++a) {
            int atom = a0 + a;
            if (atom < N_ATOMS) out[atom] = p[a] + bias;
        }
    }
}

extern "C" void kernel_launch(void* const* d_in, const int* in_sizes, int n_in,
                              void* d_out, int out_size, void* d_ws, size_t ws_size,
                              hipStream_t stream) {
    const int*   Z      = (const int*)d_in[0];
    const int*   eidx   = (const int*)d_in[1];
    const float* ediff  = (const float*)d_in[2];
    const float* edist  = (const float*)d_in[3];
    const float* emb    = (const float*)d_in[4];
    const float* msg_w1 = (const float*)d_in[5];
    const float* msg_b1 = (const float*)d_in[6];
    const float* msg_w2 = (const float*)d_in[7];
    const float* msg_b2 = (const float*)d_in[8];
    const float* filt_w = (const float*)d_in[9];
    const float* filt_b = (const float*)d_in[10];
    const float* upd_U  = (const float*)d_in[11];
    const float* upd_V  = (const float*)d_in[12];
    const float* upd_w1 = (const float*)d_in[13];
    const float* upd_b1 = (const float*)d_in[14];
    const float* upd_w2 = (const float*)d_in[15];
    const float* upd_b2 = (const float*)d_in[16];
    const float* ro_w1  = (const float*)d_in[17];
    const float* ro_b1  = (const float*)d_in[18];
    const float* ro_w2  = (const float*)d_in[19];
    const float* ro_b2  = (const float*)d_in[20];
    float* out = (float*)d_out;

    float* ws  = (float*)d_ws;
    float* s    = ws;                     // N*F fp32
    float* v    = s + N_ATOMS * F;        // N*3F fp32
    float* ds   = v + N_ATOMS * 3 * F;    // N*F fp32
    float* dv   = ds + N_ATOMS * F;       // N*3F fp32
    int* count  = (int*)(dv + N_ATOMS * 3 * F);  // N
    int* bucket = count + N_ATOMS;               // N*CAP
    float* wT   = (float*)(bucket + N_ATOMS * CAP);

    const int L_W1T = F * F, L_W2T = F * 3 * F, L_UT = F * F, L_VT = F * F,
              L_UW1T = 2 * F * F, L_UW2T = F * 3 * F;
    const int LAYER_T = L_W1T + L_W2T + L_UT + L_VT + L_UW1T + L_UW2T;
    float* w1T_base  = wT;
    float* w2T_base  = wT + L_W1T;
    float* UT_base   = wT + L_W1T + L_W2T;
    float* VT_base   = wT + L_W1T + L_W2T + L_UT;
    float* uw1T_base = wT + L_W1T + L_W2T + L_UT + L_VT;
    float* uw2T_base = wT + L_W1T + L_W2T + L_UT + L_VT + L_UW1T;
    float* roT       = wT + (size_t)NL * LAYER_T;   // [64][F]
    __half* phi_h = (__half*)(roT + F * 64);            // N*3F half
    __half* v_h   = phi_h + (size_t)N_ATOMS * 3 * F;    // N*3F half

    TPlans P;
    int nb = 0, pi = 0;
    auto add = [&](const float* src, float* dst, int R, int C) {
        P.p[pi].src = src; P.p[pi].dst = dst; P.p[pi].R = R; P.p[pi].C = C;
        P.p[pi].blk0 = nb;
        nb += (R * C + 255) / 256; ++pi;
    };
    for (int l = 0; l < NL; ++l) {
        add(msg_w1 + l * F * F,     w1T_base  + l * LAYER_T, F, F);
        add(msg_w2 + l * F * 3 * F, w2T_base  + l * LAYER_T, F, 3 * F);
        add(upd_U  + l * F * F,     UT_base   + l * LAYER_T, F, F);
        add(upd_V  + l * F * F,     VT_base   + l * LAYER_T, F, F);
        add(upd_w1 + l * 2 * F * F, uw1T_base + l * LAYER_T, 2 * F, F);
        add(upd_w2 + l * F * 3 * F, uw2T_base + l * LAYER_T, F, 3 * F);
    }
    add(ro_w1, roT, F, 64);
    P.n = pi;

    init_kernel<<<N_ATOMS, F, 0, stream>>>(Z, emb, s);
    hipMemsetAsync(v, 0, (size_t)N_ATOMS * 3 * F * sizeof(float), stream);
    hipMemsetAsync(v_h, 0, (size_t)N_ATOMS * 3 * F * sizeof(__half), stream);
    hipMemsetAsync(count, 0, (size_t)N_ATOMS * sizeof(int), stream);
    fill_buckets<<<(N_EDGES + 255) / 256, 256, 0, stream>>>(eidx, count, bucket);
    transpose_all<<<nb, 256, 0, stream>>>(P);

    for (int l = 0; l < NL; ++l) {
        phi_kernel<<<N_ATOMS / 8, 128, 0, stream>>>(
            s, w1T_base + l * LAYER_T, msg_b1 + l * F,
            w2T_base + l * LAYER_T, msg_b2 + l * 3 * F, phi_h);
        edge_agg_kernel<<<N_ATOMS, 256, 0, stream>>>(
            count, bucket, eidx, ediff, edist,
            filt_w + l * B * 3 * F, filt_b + l * 3 * F, phi_h, v_h, ds, dv);
        update_kernel<<<N_ATOMS / 8, 128, 0, stream>>>(
            s, v, v_h, ds, dv, UT_base + l * LAYER_T, VT_base + l * LAYER_T,
            uw1T_base + l * LAYER_T, upd_b1 + l * F,
            uw2T_base + l * LAYER_T, upd_b2 + l * 3 * F);
    }
    readout_kernel<<<(N_ATOMS + 15) / 16, 64, 0, stream>>>(s, roT, ro_b1, ro_w2, ro_b2, out);
}

// Round 8
// 513.187 us; speedup vs baseline: 1.7517x; 1.1278x over previous
//
#include <hip/hip_runtime.h>
#include <hip/hip_bf16.h>
#include <hip/hip_fp16.h>
#include <math.h>

#define N_ATOMS 5000
#define N_EDGES 100000
#define F 128
#define B 20
#define NL 3
#define CAP 96

constexpr float CUTOFF = 5.0f;
constexpr float PI_F = 3.14159265358979323846f;

typedef _Float16 f16x8 __attribute__((ext_vector_type(8)));
typedef float f32x4 __attribute__((ext_vector_type(4)));

__device__ __forceinline__ float silu_f(float x) { return x / (1.0f + __expf(-x)); }

// ---------------------------------------------------------------- init: s = emb[Z] (f32 + f16)
__global__ void init_kernel(const int* __restrict__ Z, const float* __restrict__ emb,
                            float* __restrict__ s, _Float16* __restrict__ s_h) {
    int atom = blockIdx.x;
    int t = threadIdx.x;
    float val = emb[Z[atom] * F + t];
    s[atom * F + t] = val;
    s_h[atom * F + t] = (_Float16)val;
}

// ---------------------------------------------------------------- bucket edges by dst
__global__ void fill_buckets(const int* __restrict__ eidx, int* __restrict__ count,
                             int* __restrict__ bucket) {
    int e = blockIdx.x * 256 + threadIdx.x;
    if (e >= N_EDGES) return;
    int dst = eidx[2 * e];
    int pos = atomicAdd(&count[dst], 1);
    if (pos < CAP) bucket[dst * CAP + pos] = e;
}

// ---------------------------------------------------------------- transpose (f32 dst; used for readout weights)
struct TPlan { const float* src; float* dst; int R, C, blk0; };
struct TPlans { TPlan p[4]; int n; };

__global__ void transpose_all(TPlans P) {
    int b = blockIdx.x;
    int pi = 0;
    for (int i = 1; i < 4; ++i)
        if (i < P.n && b >= P.p[i].blk0) pi = i;
    const float* src = P.p[pi].src;
    float* dst = P.p[pi].dst;
    int R = P.p[pi].R, C = P.p[pi].C;
    int f = (b - P.p[pi].blk0) * 256 + threadIdx.x;
    if (f < R * C) {
        int c = f / R, r = f - c * R;
        dst[f] = src[r * C + c];
    }
}

// ---------------------------------------------------------------- transpose to f16: WT[n][k] = W[k][n]
struct TPlanH { const float* src; _Float16* dst; int R, C, blk0; };
struct TPlansH { TPlanH p[20]; int n; };

__global__ void transpose_h(TPlansH P) {
    int b = blockIdx.x;
    int pi = 0;
#pragma unroll
    for (int i = 1; i < 20; ++i)
        if (i < P.n && b >= P.p[i].blk0) pi = i;
    const float* src = P.p[pi].src;
    _Float16* dst = P.p[pi].dst;
    int R = P.p[pi].R, C = P.p[pi].C;
    int f = (b - P.p[pi].blk0) * 256 + threadIdx.x;
    if (f < R * C) {
        int c = f / R, r = f - c * R;
        dst[f] = (_Float16)src[r * C + c];
    }
}

// ---------------------------------------------------------------- MFMA GEMM: C = [silu](A @ W + bias)
// A [M x K] f16 row-major; WT [N x K] f16 (row n = column n of W); out f16 and/or f32.
// A-frag: A[m=lane&15][k=quad*8+j]; B-frag: WT[n=lane&15][k=quad*8+j];
// C/D: row=quad*4+r, col=lane&15  (gfx950 16x16x32, layouts per m89/m120).
// Block = 4 waves; wave handles 4 consecutive m-tiles at one n-tile.
template<int KT>
__global__ __launch_bounds__(256) void gemm_kernel(
    const _Float16* __restrict__ A, const _Float16* __restrict__ WT,
    const float* __restrict__ bias, _Float16* __restrict__ Cf16,
    float* __restrict__ Cf32, int M, int N, int Mtiles, int Mchunks, int dosilu) {
    constexpr int K = KT * 32;
    int lane = threadIdx.x & 63;
    int wv = threadIdx.x >> 6;
    int mc = blockIdx.y * 4 + wv;
    if (mc >= Mchunks) return;
    int nt = blockIdx.x;
    int n = nt * 16 + (lane & 15);
    int quad = lane >> 4;

    f16x8 bfr[KT];
#pragma unroll
    for (int kt = 0; kt < KT; ++kt)
        bfr[kt] = *(const f16x8*)(WT + (size_t)n * K + kt * 32 + quad * 8);
    float bval = bias ? bias[n] : 0.0f;

#pragma unroll
    for (int i = 0; i < 4; ++i) {
        int mtile = mc * 4 + i;
        if (mtile >= Mtiles) break;
        int mrow = mtile * 16 + (lane & 15);
        if (mrow >= M) mrow = M - 1;   // clamped loads feed only rows >= M (not stored)
        f32x4 acc = {0.f, 0.f, 0.f, 0.f};
#pragma unroll
        for (int kt = 0; kt < KT; ++kt) {
            f16x8 afr = *(const f16x8*)(A + (size_t)mrow * K + kt * 32 + quad * 8);
            acc = __builtin_amdgcn_mfma_f32_16x16x32_f16(afr, bfr[kt], acc, 0, 0, 0);
        }
#pragma unroll
        for (int r = 0; r < 4; ++r) {
            int row = mtile * 16 + quad * 4 + r;
            if (row < M) {
                float val = acc[r] + bval;
                if (dosilu) val = silu_f(val);
                if (Cf16) Cf16[(size_t)row * N + n] = (_Float16)val;
                if (Cf32) Cf32[(size_t)row * N + n] = val;
            }
        }
    }
}

// ---------------------------------------------------------------- per-dst edge aggregation
// 256 threads = 2 edge-teams x 128 feature threads (round-7 structure).
// Now applies s/v updates in place and emits f16 shadows for the GEMMs.
__global__ __launch_bounds__(256) void edge_agg_kernel(
    const int* __restrict__ count, const int* __restrict__ bucket,
    const int* __restrict__ eidx, const float* __restrict__ ediff,
    const float* __restrict__ edist,
    const float* __restrict__ fw, const float* __restrict__ fb,
    const _Float16* __restrict__ phi_h, const _Float16* __restrict__ v_h,
    float* __restrict__ s, float* __restrict__ v,
    _Float16* __restrict__ concat_h, _Float16* __restrict__ vmid_h) {
    int a = blockIdx.x;
    int tid = threadIdx.x;
    int t = tid & 127;
    int team = tid >> 7;

    float rfw0[B], rfw1[B], rfw2[B];
#pragma unroll
    for (int b = 0; b < B; ++b) {
        const float* row = fw + b * 3 * F;
        rfw0[b] = row[t]; rfw1[b] = row[F + t]; rfw2[b] = row[2 * F + t];
    }
    float fb0 = fb[t], fb1 = fb[F + t], fb2 = fb[2 * F + t];

    int n = count[a]; if (n > CAP) n = CAP;
    float accS = 0.f, accV0 = 0.f, accV1 = 0.f, accV2 = 0.f;

    __shared__ __align__(16) float sh_rbf[32][B];
    __shared__ float sh_env[32];
    __shared__ float sh_unit[32][3];
    __shared__ int sh_src[32];
    __shared__ __align__(16) float sh_part[4][F];
    const int* bptr = bucket + a * CAP;

    for (int base = 0; base < n; base += 32) {
        int cnt = min(32, n - base);
        __syncthreads();
        if (tid < cnt) {
            int e = bptr[base + tid];
            sh_src[tid] = eidx[2 * e + 1];
            float d = edist[e];
            float fc = 0.5f * (cosf(PI_F * d / CUTOFF) + 1.0f);
            sh_env[tid] = (d < CUTOFF) ? fc : 0.0f;
            float inv = 1.0f / d;
            sh_unit[tid][0] = ediff[3 * e + 0] * inv;
            sh_unit[tid][1] = ediff[3 * e + 1] * inv;
            sh_unit[tid][2] = ediff[3 * e + 2] * inv;
        }
        for (int task = tid; task < cnt * B; task += 256) {
            int i = task / B, b = task - i * B;
            int e = bptr[base + i];
            float d = edist[e];
            sh_rbf[i][b] = sinf(d * (float)(b + 1) * (PI_F / CUTOFF)) / d;
        }
        __syncthreads();

        int myCnt = (cnt > team) ? ((cnt - team + 1) >> 1) : 0;
        if (myCnt > 0) {
            _Float16 PA[4][3], VA[4][3], PB[4][3], VB[4][3];
            int ngrp = (myCnt + 3) >> 2;

            auto load_grp = [&](int gbase, _Float16 P[4][3], _Float16 V4[4][3]) {
#pragma unroll
                for (int j = 0; j < 4; ++j) {
                    int i = gbase + j;
                    int ii = (i < myCnt) ? i : (myCnt - 1);
                    int src = sh_src[team + 2 * ii];
                    const _Float16* ps = phi_h + (size_t)src * 3 * F;
                    const _Float16* vs = v_h + (size_t)src * 3 * F;
                    P[j][0] = ps[t]; P[j][1] = ps[F + t]; P[j][2] = ps[2 * F + t];
                    V4[j][0] = vs[t]; V4[j][1] = vs[F + t]; V4[j][2] = vs[2 * F + t];
                }
            };
            auto comp_grp = [&](int gbase, _Float16 P[4][3], _Float16 V4[4][3]) {
#pragma unroll
                for (int j = 0; j < 4; ++j) {
                    int i = gbase + j;
                    if (i < myCnt) {
                        int ei = team + 2 * i;
                        float f0 = fb0, f1 = fb1, f2 = fb2;
#pragma unroll
                        for (int b = 0; b < B; ++b) {
                            float r = sh_rbf[ei][b];
                            f0 += r * rfw0[b]; f1 += r * rfw1[b]; f2 += r * rfw2[b];
                        }
                        float env = sh_env[ei];
                        f0 *= env; f1 *= env; f2 *= env;
                        accS += f2 * (float)P[j][2];
                        float gsv = f0 * (float)P[j][0];
                        float gev = f1 * (float)P[j][1];
                        accV0 += (float)V4[j][0] * gsv + gev * sh_unit[ei][0];
                        accV1 += (float)V4[j][1] * gsv + gev * sh_unit[ei][1];
                        accV2 += (float)V4[j][2] * gsv + gev * sh_unit[ei][2];
                    }
                }
            };

            load_grp(0, PA, VA);
            for (int g = 0; g < ngrp; g += 2) {
                if (g + 1 < ngrp) load_grp((g + 1) * 4, PB, VB);
                comp_grp(g * 4, PA, VA);
                if (g + 1 < ngrp) {
                    if (g + 2 < ngrp) load_grp((g + 2) * 4, PA, VA);
                    comp_grp((g + 1) * 4, PB, VB);
                }
            }
        }
    }

    __syncthreads();
    if (team == 1) {
        sh_part[0][t] = accS; sh_part[1][t] = accV0;
        sh_part[2][t] = accV1; sh_part[3][t] = accV2;
    }
    __syncthreads();
    if (team == 0) {
        float sm = s[a * F + t] + accS + sh_part[0][t];
        s[a * F + t] = sm;
        concat_h[(size_t)a * 256 + t] = (_Float16)sm;
        float vm0 = v[a * 3 * F + t] + accV0 + sh_part[1][t];
        float vm1 = v[a * 3 * F + F + t] + accV1 + sh_part[2][t];
        float vm2 = v[a * 3 * F + 2 * F + t] + accV2 + sh_part[3][t];
        v[a * 3 * F + t] = vm0;
        v[a * 3 * F + F + t] = vm1;
        v[a * 3 * F + 2 * F + t] = vm2;
        vmid_h[(size_t)(a * 3 + 0) * F + t] = (_Float16)vm0;
        vmid_h[(size_t)(a * 3 + 1) * F + t] = (_Float16)vm1;
        vmid_h[(size_t)(a * 3 + 2) * F + t] = (_Float16)vm2;
    }
}

// ---------------------------------------------------------------- Vn: concat[:,128+t] = ||Vv||
__global__ __launch_bounds__(256) void vn_kernel(const _Float16* __restrict__ UV,
                                                 _Float16* __restrict__ concat_h) {
    int idx = blockIdx.x * 256 + threadIdx.x;
    if (idx >= N_ATOMS * F) return;
    int a = idx >> 7, t = idx & 127;
    float x0 = (float)UV[(size_t)(a * 3 + 0) * 256 + 128 + t];
    float x1 = (float)UV[(size_t)(a * 3 + 1) * 256 + 128 + t];
    float x2 = (float)UV[(size_t)(a * 3 + 2) * 256 + 128 + t];
    concat_h[(size_t)a * 256 + 128 + t] = (_Float16)sqrtf(x0 * x0 + x1 * x1 + x2 * x2);
}

// ---------------------------------------------------------------- final: v += avv*Uv; s += asv*dot + ass
__global__ __launch_bounds__(256) void final_kernel(
    const _Float16* __restrict__ UV, const _Float16* __restrict__ aout_h,
    float* __restrict__ s, float* __restrict__ v,
    _Float16* __restrict__ s_h, _Float16* __restrict__ v_h) {
    int idx = blockIdx.x * 256 + threadIdx.x;
    if (idx >= N_ATOMS * F) return;
    int a = idx >> 7, t = idx & 127;
    float avv = (float)aout_h[(size_t)a * 384 + t];
    float asv = (float)aout_h[(size_t)a * 384 + 128 + t];
    float ass = (float)aout_h[(size_t)a * 384 + 256 + t];
    float dot = 0.f;
#pragma unroll
    for (int d = 0; d < 3; ++d) {
        float u = (float)UV[(size_t)(a * 3 + d) * 256 + t];
        float w = (float)UV[(size_t)(a * 3 + d) * 256 + 128 + t];
        dot += u * w;
        float nv = v[a * 3 * F + d * F + t] + avv * u;
        v[a * 3 * F + d * F + t] = nv;
        v_h[(size_t)a * 3 * F + d * F + t] = (_Float16)nv;
    }
    float sn = s[a * F + t] + asv * dot + ass;
    s[a * F + t] = sn;
    s_h[(size_t)a * F + t] = (_Float16)sn;
}

// ---------------------------------------------------------------- readout, 16 atoms/block, 64 threads
__global__ __launch_bounds__(64) void readout_kernel(
    const float* __restrict__ s, const float* __restrict__ w1T,
    const float* __restrict__ b1,
    const float* __restrict__ w2, const float* __restrict__ b2, float* __restrict__ out) {
    const int TA = 16;
    __shared__ __align__(16) float sh_s[F][20];
    int a0 = blockIdx.x * TA;
    int t = threadIdx.x;
#pragma unroll
    for (int a = 0; a < TA; ++a) {
        int atom = a0 + a;
        sh_s[t][a]      = (atom < N_ATOMS) ? s[atom * F + t] : 0.0f;
        sh_s[t + 64][a] = (atom < N_ATOMS) ? s[atom * F + 64 + t] : 0.0f;
    }
    __syncthreads();
    float acc[TA];
    float bb = b1[t];
#pragma unroll
    for (int a = 0; a < TA; ++a) acc[a] = bb;
    const float* wr = w1T + t * F;
#pragma unroll 2
    for (int k = 0; k < F; k += 4) {
        float4 wq = *(const float4*)(wr + k);
        float wj[4] = {wq.x, wq.y, wq.z, wq.w};
#pragma unroll
        for (int j = 0; j < 4; ++j) {
            const float* rp = &sh_s[k + j][0];
            float4 q0 = *(const float4*)(rp), q1 = *(const float4*)(rp + 4);
            float4 q2 = *(const float4*)(rp + 8), q3 = *(const float4*)(rp + 12);
            float sv[TA] = {q0.x, q0.y, q0.z, q0.w, q1.x, q1.y, q1.z, q1.w,
                            q2.x, q2.y, q2.z, q2.w, q3.x, q3.y, q3.z, q3.w};
#pragma unroll
            for (int a = 0; a < TA; ++a) acc[a] += sv[a] * wj[j];
        }
    }
    float w2t = w2[t];
    float p[TA];
#pragma unroll
    for (int a = 0; a < TA; ++a) p[a] = silu_f(acc[a]) * w2t;
#pragma unroll
    for (int a = 0; a < TA; ++a)
#pragma unroll
        for (int off = 32; off > 0; off >>= 1) p[a] += __shfl_down(p[a], off, 64);
    if (t == 0) {
        float bias = b2[0];
#pragma unroll
        for (int a = 0; a < TA; ++a) {
            int atom = a0 + a;
            if (atom < N_ATOMS) out[atom] = p[a] + bias;
        }
    }
}

extern "C" void kernel_launch(void* const* d_in, const int* in_sizes, int n_in,
                              void* d_out, int out_size, void* d_ws, size_t ws_size,
                              hipStream_t stream) {
    const int*   Z      = (const int*)d_in[0];
    const int*   eidx   = (const int*)d_in[1];
    const float* ediff  = (const float*)d_in[2];
    const float* edist  = (const float*)d_in[3];
    const float* emb    = (const float*)d_in[4];
    const float* msg_w1 = (const float*)d_in[5];
    const float* msg_b1 = (const float*)d_in[6];
    const float* msg_w2 = (const float*)d_in[7];
    const float* msg_b2 = (const float*)d_in[8];
    const float* filt_w = (const float*)d_in[9];
    const float* filt_b = (const float*)d_in[10];
    const float* upd_U  = (const float*)d_in[11];
    const float* upd_V  = (const float*)d_in[12];
    const float* upd_w1 = (const float*)d_in[13];
    const float* upd_b1 = (const float*)d_in[14];
    const float* upd_w2 = (const float*)d_in[15];
    const float* upd_b2 = (const float*)d_in[16];
    const float* ro_w1  = (const float*)d_in[17];
    const float* ro_b1  = (const float*)d_in[18];
    const float* ro_w2  = (const float*)d_in[19];
    const float* ro_b2  = (const float*)d_in[20];
    float* out = (float*)d_out;

    // ---------------- workspace layout ----------------
    float* ws = (float*)d_ws;
    float* s   = ws;                      // N*F f32
    float* v   = s + N_ATOMS * F;         // N*3F f32
    float* roT = v + N_ATOMS * 3 * F;     // 64*F f32 (readout W1 transposed)
    int* count  = (int*)(roT + 64 * F);   // N
    int* bucket = count + N_ATOMS;        // N*CAP
    _Float16* hbase = (_Float16*)(bucket + N_ATOMS * CAP);
    _Float16* s_h      = hbase;                               // N*F
    _Float16* v_h      = s_h + (size_t)N_ATOMS * F;           // N*3F
    _Float16* vmid_h   = v_h + (size_t)N_ATOMS * 3 * F;       // N*3F
    _Float16* phi_h    = vmid_h + (size_t)N_ATOMS * 3 * F;    // N*3F (aliased as aout after edge_agg)
    _Float16* hid_h    = phi_h + (size_t)N_ATOMS * 3 * F;     // N*F
    _Float16* concat_h = hid_h + (size_t)N_ATOMS * F;         // N*2F
    _Float16* UV       = concat_h + (size_t)N_ATOMS * 2 * F;  // (N*3)*2F
    _Float16* wh       = UV + (size_t)N_ATOMS * 3 * 2 * F;    // f16 weights

    const int HWL = 16384 + 49152 + 32768 + 32768 + 49152;    // 180224 halves/layer
    _Float16* mw1T = wh;                  // [128][128]
    _Float16* mw2T = wh + 16384;          // [384][128]
    _Float16* uvT  = wh + 65536;          // [256][128] rows 0-127=U^T, 128-255=V^T
    _Float16* uw1T = wh + 98304;          // [128][256]
    _Float16* uw2T = wh + 131072;         // [384][128]

    // ---------------- transpose plans ----------------
    TPlansH PH; int nbh = 0, pih = 0;
    auto addh = [&](const float* src, _Float16* dst, int R, int C) {
        PH.p[pih].src = src; PH.p[pih].dst = dst; PH.p[pih].R = R; PH.p[pih].C = C;
        PH.p[pih].blk0 = nbh;
        nbh += (R * C + 255) / 256; ++pih;
    };
    for (int l = 0; l < NL; ++l) {
        addh(msg_w1 + l * F * F,     mw1T + (size_t)l * HWL, F, F);
        addh(msg_w2 + l * F * 3 * F, mw2T + (size_t)l * HWL, F, 3 * F);
        addh(upd_U  + l * F * F,     uvT  + (size_t)l * HWL, F, F);
        addh(upd_V  + l * F * F,     uvT  + (size_t)l * HWL + F * F, F, F);
        addh(upd_w1 + l * 2 * F * F, uw1T + (size_t)l * HWL, 2 * F, F);
        addh(upd_w2 + l * F * 3 * F, uw2T + (size_t)l * HWL, F, 3 * F);
    }
    PH.n = pih;

    TPlans PF;
    PF.p[0].src = ro_w1; PF.p[0].dst = roT; PF.p[0].R = F; PF.p[0].C = 64; PF.p[0].blk0 = 0;
    PF.n = 1;
    int nbf = (F * 64 + 255) / 256;

    // ---------------- launch ----------------
    init_kernel<<<N_ATOMS, F, 0, stream>>>(Z, emb, s, s_h);
    hipMemsetAsync(v, 0, (size_t)N_ATOMS * 3 * F * sizeof(float), stream);
    hipMemsetAsync(v_h, 0, (size_t)N_ATOMS * 3 * F * sizeof(_Float16), stream);
    hipMemsetAsync(count, 0, (size_t)N_ATOMS * sizeof(int), stream);
    fill_buckets<<<(N_EDGES + 255) / 256, 256, 0, stream>>>(eidx, count, bucket);
    transpose_h<<<nbh, 256, 0, stream>>>(PH);
    transpose_all<<<nbf, 256, 0, stream>>>(PF);

    // GEMM geometry: Mtiles=313, Mchunks=79 for M=5000; Mtiles=938, Mchunks=235 for M=15000
    for (int l = 0; l < NL; ++l) {
        // G1: hid = silu(s @ msg_w1 + b1)
        gemm_kernel<4><<<dim3(8, 20), 256, 0, stream>>>(
            s_h, mw1T + (size_t)l * HWL, msg_b1 + l * F, hid_h, nullptr,
            N_ATOMS, 128, 313, 79, 1);
        // G2: phi = hid @ msg_w2 + b2
        gemm_kernel<4><<<dim3(24, 20), 256, 0, stream>>>(
            hid_h, mw2T + (size_t)l * HWL, msg_b2 + l * 3 * F, phi_h, nullptr,
            N_ATOMS, 384, 313, 79, 0);
        // edge aggregation -> s,v updated in place; concat_h (s part), vmid_h
        edge_agg_kernel<<<N_ATOMS, 256, 0, stream>>>(
            count, bucket, eidx, ediff, edist,
            filt_w + l * B * 3 * F, filt_b + l * 3 * F, phi_h, v_h,
            s, v, concat_h, vmid_h);
        // G3: UV = v_mid @ [U|V]
        gemm_kernel<4><<<dim3(16, 59), 256, 0, stream>>>(
            vmid_h, uvT + (size_t)l * HWL, nullptr, UV, nullptr,
            N_ATOMS * 3, 256, 938, 235, 0);
        // Vn -> concat second half
        vn_kernel<<<(N_ATOMS * F + 255) / 256, 256, 0, stream>>>(UV, concat_h);
        // G4: hid = silu(concat @ upd_w1 + b1)  (K=256)
        gemm_kernel<8><<<dim3(8, 20), 256, 0, stream>>>(
            concat_h, uw1T + (size_t)l * HWL, upd_b1 + l * F, hid_h, nullptr,
            N_ATOMS, 128, 313, 79, 1);
        // G5: a = hid @ upd_w2 + b2  (into phi_h region, now dead)
        gemm_kernel<4><<<dim3(24, 20), 256, 0, stream>>>(
            hid_h, uw2T + (size_t)l * HWL, upd_b2 + l * 3 * F, phi_h, nullptr,
            N_ATOMS, 384, 313, 79, 0);
        // final elementwise
        final_kernel<<<(N_ATOMS * F + 255) / 256, 256, 0, stream>>>(
            UV, phi_h, s, v, s_h, v_h);
    }
    readout_kernel<<<(N_ATOMS + 15) / 16, 64, 0, stream>>>(s, roT, ro_b1, ro_w2, ro_b2, out);
}

// Round 9
// 483.303 us; speedup vs baseline: 1.8601x; 1.0618x over previous
//
#include <hip/hip_runtime.h>
#include <hip/hip_bf16.h>
#include <hip/hip_fp16.h>
#include <math.h>

#define N_ATOMS 5000
#define N_EDGES 100000
#define F 128
#define B 20
#define NL 3
#define CAP 96

constexpr float CUTOFF = 5.0f;
constexpr float PI_F = 3.14159265358979323846f;

typedef _Float16 f16x8 __attribute__((ext_vector_type(8)));
typedef float f32x4 __attribute__((ext_vector_type(4)));

__device__ __forceinline__ float silu_f(float x) { return x / (1.0f + __expf(-x)); }

// ---------------------------------------------------------------- init: s = emb[Z] (f32 + f16)
__global__ void init_kernel(const int* __restrict__ Z, const float* __restrict__ emb,
                            float* __restrict__ s, _Float16* __restrict__ s_h) {
    int atom = blockIdx.x;
    int t = threadIdx.x;
    float val = emb[Z[atom] * F + t];
    s[atom * F + t] = val;
    s_h[atom * F + t] = (_Float16)val;
}

// ---------------------------------------------------------------- bucket edges by dst
__global__ void fill_buckets(const int* __restrict__ eidx, int* __restrict__ count,
                             int* __restrict__ bucket) {
    int e = blockIdx.x * 256 + threadIdx.x;
    if (e >= N_EDGES) return;
    int dst = eidx[2 * e];
    int pos = atomicAdd(&count[dst], 1);
    if (pos < CAP) bucket[dst * CAP + pos] = e;
}

// ---------------------------------------------------------------- transpose (f16 or f32 dst)
struct TPlanX { const float* src; void* dst; int R, C, blk0, isf16; };
struct TPlansX { TPlanX p[20]; int n; };

__global__ void transpose_x(TPlansX P) {
    int b = blockIdx.x;
    int pi = 0;
#pragma unroll
    for (int i = 1; i < 20; ++i)
        if (i < P.n && b >= P.p[i].blk0) pi = i;
    const float* src = P.p[pi].src;
    int R = P.p[pi].R, C = P.p[pi].C;
    int f = (b - P.p[pi].blk0) * 256 + threadIdx.x;
    if (f < R * C) {
        int c = f / R, r = f - c * R;
        float val = src[r * C + c];
        if (P.p[pi].isf16) ((_Float16*)P.p[pi].dst)[f] = (_Float16)val;
        else ((float*)P.p[pi].dst)[f] = val;
    }
}

// ---------------------------------------------------------------- phiMLP: phi = silu(s@W1+b1)@W2+b2
// block = 16 atoms, 256 thr = 4 waves; hid lives in LDS only. MFMA 16x16x32 f16.
__global__ __launch_bounds__(256) void phi_mlp_kernel(
    const _Float16* __restrict__ s_h, const _Float16* __restrict__ w1T,  // [128][128]
    const float* __restrict__ b1, const _Float16* __restrict__ w2T,      // [384][128]
    const float* __restrict__ b2, _Float16* __restrict__ phi_h) {
    __shared__ _Float16 shA[16 * 136];
    __shared__ _Float16 shH[16 * 136];
    int r0 = blockIdx.x * 16;
    int tid = threadIdx.x;
    {
        int r = tid >> 4, c8 = (tid & 15) * 8;
        int rg = r0 + r; if (rg >= N_ATOMS) rg = N_ATOMS - 1;
        *(f16x8*)(shA + r * 136 + c8) = *(const f16x8*)(s_h + (size_t)rg * F + c8);
    }
    __syncthreads();
    int lane = tid & 63, wv = tid >> 6;
    int col = lane & 15, quad = lane >> 4;
    for (int nt = wv; nt < 8; nt += 4) {
        int n = nt * 16 + col;
        f32x4 acc = {0.f, 0.f, 0.f, 0.f};
#pragma unroll
        for (int kt = 0; kt < 4; ++kt) {
            f16x8 afr = *(const f16x8*)(shA + col * 136 + kt * 32 + quad * 8);
            f16x8 bfr = *(const f16x8*)(w1T + (size_t)n * 128 + kt * 32 + quad * 8);
            acc = __builtin_amdgcn_mfma_f32_16x16x32_f16(afr, bfr, acc, 0, 0, 0);
        }
        float bb = b1[n];
#pragma unroll
        for (int r = 0; r < 4; ++r)
            shH[(quad * 4 + r) * 136 + n] = (_Float16)silu_f(acc[r] + bb);
    }
    __syncthreads();
    for (int nt = wv; nt < 24; nt += 4) {
        int n = nt * 16 + col;
        f32x4 acc = {0.f, 0.f, 0.f, 0.f};
#pragma unroll
        for (int kt = 0; kt < 4; ++kt) {
            f16x8 afr = *(const f16x8*)(shH + col * 136 + kt * 32 + quad * 8);
            f16x8 bfr = *(const f16x8*)(w2T + (size_t)n * 128 + kt * 32 + quad * 8);
            acc = __builtin_amdgcn_mfma_f32_16x16x32_f16(afr, bfr, acc, 0, 0, 0);
        }
        float bb = b2[n];
#pragma unroll
        for (int r = 0; r < 4; ++r) {
            int row = r0 + quad * 4 + r;
            if (row < N_ATOMS) phi_h[(size_t)row * 384 + n] = (_Float16)(acc[r] + bb);
        }
    }
}

// ---------------------------------------------------------------- per-dst edge aggregation (round-8)
__global__ __launch_bounds__(256) void edge_agg_kernel(
    const int* __restrict__ count, const int* __restrict__ bucket,
    const int* __restrict__ eidx, const float* __restrict__ ediff,
    const float* __restrict__ edist,
    const float* __restrict__ fw, const float* __restrict__ fb,
    const _Float16* __restrict__ phi_h, const _Float16* __restrict__ v_h,
    float* __restrict__ s, float* __restrict__ v,
    _Float16* __restrict__ concat_h, _Float16* __restrict__ vmid_h) {
    int a = blockIdx.x;
    int tid = threadIdx.x;
    int t = tid & 127;
    int team = tid >> 7;

    float rfw0[B], rfw1[B], rfw2[B];
#pragma unroll
    for (int b = 0; b < B; ++b) {
        const float* row = fw + b * 3 * F;
        rfw0[b] = row[t]; rfw1[b] = row[F + t]; rfw2[b] = row[2 * F + t];
    }
    float fb0 = fb[t], fb1 = fb[F + t], fb2 = fb[2 * F + t];

    int n = count[a]; if (n > CAP) n = CAP;
    float accS = 0.f, accV0 = 0.f, accV1 = 0.f, accV2 = 0.f;

    __shared__ __align__(16) float sh_rbf[32][B];
    __shared__ float sh_env[32];
    __shared__ float sh_unit[32][3];
    __shared__ int sh_src[32];
    __shared__ __align__(16) float sh_part[4][F];
    const int* bptr = bucket + a * CAP;

    for (int base = 0; base < n; base += 32) {
        int cnt = min(32, n - base);
        __syncthreads();
        if (tid < cnt) {
            int e = bptr[base + tid];
            sh_src[tid] = eidx[2 * e + 1];
            float d = edist[e];
            float fc = 0.5f * (cosf(PI_F * d / CUTOFF) + 1.0f);
            sh_env[tid] = (d < CUTOFF) ? fc : 0.0f;
            float inv = 1.0f / d;
            sh_unit[tid][0] = ediff[3 * e + 0] * inv;
            sh_unit[tid][1] = ediff[3 * e + 1] * inv;
            sh_unit[tid][2] = ediff[3 * e + 2] * inv;
        }
        for (int task = tid; task < cnt * B; task += 256) {
            int i = task / B, b = task - i * B;
            int e = bptr[base + i];
            float d = edist[e];
            sh_rbf[i][b] = sinf(d * (float)(b + 1) * (PI_F / CUTOFF)) / d;
        }
        __syncthreads();

        int myCnt = (cnt > team) ? ((cnt - team + 1) >> 1) : 0;
        if (myCnt > 0) {
            _Float16 PA[4][3], VA[4][3], PB[4][3], VB[4][3];
            int ngrp = (myCnt + 3) >> 2;

            auto load_grp = [&](int gbase, _Float16 P[4][3], _Float16 V4[4][3]) {
#pragma unroll
                for (int j = 0; j < 4; ++j) {
                    int i = gbase + j;
                    int ii = (i < myCnt) ? i : (myCnt - 1);
                    int src = sh_src[team + 2 * ii];
                    const _Float16* ps = phi_h + (size_t)src * 3 * F;
                    const _Float16* vs = v_h + (size_t)src * 3 * F;
                    P[j][0] = ps[t]; P[j][1] = ps[F + t]; P[j][2] = ps[2 * F + t];
                    V4[j][0] = vs[t]; V4[j][1] = vs[F + t]; V4[j][2] = vs[2 * F + t];
                }
            };
            auto comp_grp = [&](int gbase, _Float16 P[4][3], _Float16 V4[4][3]) {
#pragma unroll
                for (int j = 0; j < 4; ++j) {
                    int i = gbase + j;
                    if (i < myCnt) {
                        int ei = team + 2 * i;
                        float f0 = fb0, f1 = fb1, f2 = fb2;
#pragma unroll
                        for (int b = 0; b < B; ++b) {
                            float r = sh_rbf[ei][b];
                            f0 += r * rfw0[b]; f1 += r * rfw1[b]; f2 += r * rfw2[b];
                        }
                        float env = sh_env[ei];
                        f0 *= env; f1 *= env; f2 *= env;
                        accS += f2 * (float)P[j][2];
                        float gsv = f0 * (float)P[j][0];
                        float gev = f1 * (float)P[j][1];
                        accV0 += (float)V4[j][0] * gsv + gev * sh_unit[ei][0];
                        accV1 += (float)V4[j][1] * gsv + gev * sh_unit[ei][1];
                        accV2 += (float)V4[j][2] * gsv + gev * sh_unit[ei][2];
                    }
                }
            };

            load_grp(0, PA, VA);
            for (int g = 0; g < ngrp; g += 2) {
                if (g + 1 < ngrp) load_grp((g + 1) * 4, PB, VB);
                comp_grp(g * 4, PA, VA);
                if (g + 1 < ngrp) {
                    if (g + 2 < ngrp) load_grp((g + 2) * 4, PA, VA);
                    comp_grp((g + 1) * 4, PB, VB);
                }
            }
        }
    }

    __syncthreads();
    if (team == 1) {
        sh_part[0][t] = accS; sh_part[1][t] = accV0;
        sh_part[2][t] = accV1; sh_part[3][t] = accV2;
    }
    __syncthreads();
    if (team == 0) {
        float sm = s[a * F + t] + accS + sh_part[0][t];
        s[a * F + t] = sm;
        concat_h[(size_t)a * 256 + t] = (_Float16)sm;
        float vm0 = v[a * 3 * F + t] + accV0 + sh_part[1][t];
        float vm1 = v[a * 3 * F + F + t] + accV1 + sh_part[2][t];
        float vm2 = v[a * 3 * F + 2 * F + t] + accV2 + sh_part[3][t];
        v[a * 3 * F + t] = vm0;
        v[a * 3 * F + F + t] = vm1;
        v[a * 3 * F + 2 * F + t] = vm2;
        vmid_h[(size_t)(a * 3 + 0) * F + t] = (_Float16)vm0;
        vmid_h[(size_t)(a * 3 + 1) * F + t] = (_Float16)vm1;
        vmid_h[(size_t)(a * 3 + 2) * F + t] = (_Float16)vm2;
    }
}

// ---------------------------------------------------------------- uvgemm+vn: UV = vmid @ [U|V]; concat[:,128+]=||Vv||
// block = 16 atoms = 48 rows x 16 n-tiles; Vv partials stashed in LDS f32.
__global__ __launch_bounds__(256) void uvgemm_vn_kernel(
    const _Float16* __restrict__ vmid_h, const _Float16* __restrict__ uvT,  // [256][128]
    _Float16* __restrict__ UV, _Float16* __restrict__ concat_h) {
    __shared__ _Float16 shA[48 * 136];
    __shared__ float shVv[48 * 132];
    int a0 = blockIdx.x * 16;
    int r0 = a0 * 3;
    int tid = threadIdx.x;
    for (int slot = tid; slot < 48 * 16; slot += 256) {
        int r = slot >> 4, c8 = (slot & 15) * 8;
        int rg = r0 + r; if (rg >= N_ATOMS * 3) rg = N_ATOMS * 3 - 1;
        *(f16x8*)(shA + r * 136 + c8) = *(const f16x8*)(vmid_h + (size_t)rg * F + c8);
    }
    __syncthreads();
    int lane = tid & 63, wv = tid >> 6;
    int col = lane & 15, quad = lane >> 4;
    for (int j = wv; j < 48; j += 4) {
        int mt = j >> 4, nt = j & 15;
        int n = nt * 16 + col;
        f32x4 acc = {0.f, 0.f, 0.f, 0.f};
#pragma unroll
        for (int kt = 0; kt < 4; ++kt) {
            f16x8 afr = *(const f16x8*)(shA + (mt * 16 + col) * 136 + kt * 32 + quad * 8);
            f16x8 bfr = *(const f16x8*)(uvT + (size_t)n * 128 + kt * 32 + quad * 8);
            acc = __builtin_amdgcn_mfma_f32_16x16x32_f16(afr, bfr, acc, 0, 0, 0);
        }
#pragma unroll
        for (int r = 0; r < 4; ++r) {
            int rl = mt * 16 + quad * 4 + r;
            int row = r0 + rl;
            float val = acc[r];
            if (row < N_ATOMS * 3) UV[(size_t)row * 256 + n] = (_Float16)val;
            if (nt >= 8) shVv[rl * 132 + (n - 128)] = val;
        }
    }
    __syncthreads();
    for (int p = tid; p < 2048; p += 256) {
        int ai = p >> 7, t = p & 127;
        int atom = a0 + ai;
        if (atom >= N_ATOMS) break;
        float x0 = shVv[(ai * 3 + 0) * 132 + t];
        float x1 = shVv[(ai * 3 + 1) * 132 + t];
        float x2 = shVv[(ai * 3 + 2) * 132 + t];
        concat_h[(size_t)atom * 256 + 128 + t] = (_Float16)sqrtf(x0 * x0 + x1 * x1 + x2 * x2);
    }
}

// ---------------------------------------------------------------- updMLP: a = silu(concat@w1+b1)@w2+b2; final update
__global__ __launch_bounds__(256) void upd_mlp_kernel(
    const _Float16* __restrict__ concat_h, const _Float16* __restrict__ w1T,  // [128][256]
    const float* __restrict__ b1, const _Float16* __restrict__ w2T,           // [384][128]
    const float* __restrict__ b2, const _Float16* __restrict__ UV,
    float* __restrict__ s, float* __restrict__ v,
    _Float16* __restrict__ s_h, _Float16* __restrict__ v_h) {
    __shared__ _Float16 shA[16 * 264];
    __shared__ _Float16 shH[16 * 136];
    __shared__ float sh_a[16 * 392];
    int a0 = blockIdx.x * 16;
    int tid = threadIdx.x;
    {
        int r = tid >> 4, c16 = (tid & 15) * 16;
        int rg = a0 + r; if (rg >= N_ATOMS) rg = N_ATOMS - 1;
        *(f16x8*)(shA + r * 264 + c16) = *(const f16x8*)(concat_h + (size_t)rg * 256 + c16);
        *(f16x8*)(shA + r * 264 + c16 + 8) = *(const f16x8*)(concat_h + (size_t)rg * 256 + c16 + 8);
    }
    __syncthreads();
    int lane = tid & 63, wv = tid >> 6;
    int col = lane & 15, quad = lane >> 4;
    for (int nt = wv; nt < 8; nt += 4) {
        int n = nt * 16 + col;
        f32x4 acc = {0.f, 0.f, 0.f, 0.f};
#pragma unroll
        for (int kt = 0; kt < 8; ++kt) {
            f16x8 afr = *(const f16x8*)(shA + col * 264 + kt * 32 + quad * 8);
            f16x8 bfr = *(const f16x8*)(w1T + (size_t)n * 256 + kt * 32 + quad * 8);
            acc = __builtin_amdgcn_mfma_f32_16x16x32_f16(afr, bfr, acc, 0, 0, 0);
        }
        float bb = b1[n];
#pragma unroll
        for (int r = 0; r < 4; ++r)
            shH[(quad * 4 + r) * 136 + n] = (_Float16)silu_f(acc[r] + bb);
    }
    __syncthreads();
    for (int nt = wv; nt < 24; nt += 4) {
        int n = nt * 16 + col;
        f32x4 acc = {0.f, 0.f, 0.f, 0.f};
#pragma unroll
        for (int kt = 0; kt < 4; ++kt) {
            f16x8 afr = *(const f16x8*)(shH + col * 136 + kt * 32 + quad * 8);
            f16x8 bfr = *(const f16x8*)(w2T + (size_t)n * 128 + kt * 32 + quad * 8);
            acc = __builtin_amdgcn_mfma_f32_16x16x32_f16(afr, bfr, acc, 0, 0, 0);
        }
        float bb = b2[n];
#pragma unroll
        for (int r = 0; r < 4; ++r)
            sh_a[(quad * 4 + r) * 392 + n] = acc[r] + bb;
    }
    __syncthreads();
    for (int p = tid; p < 2048; p += 256) {
        int ai = p >> 7, t = p & 127;
        int atom = a0 + ai;
        if (atom >= N_ATOMS) break;
        float avv = sh_a[ai * 392 + t];
        float asv = sh_a[ai * 392 + 128 + t];
        float ass = sh_a[ai * 392 + 256 + t];
        float dot = 0.f;
#pragma unroll
        for (int d = 0; d < 3; ++d) {
            float u = (float)UV[(size_t)(atom * 3 + d) * 256 + t];
            float w = (float)UV[(size_t)(atom * 3 + d) * 256 + 128 + t];
            dot += u * w;
            float nv = v[(size_t)atom * 3 * F + d * F + t] + avv * u;
            v[(size_t)atom * 3 * F + d * F + t] = nv;
            v_h[(size_t)atom * 3 * F + d * F + t] = (_Float16)nv;
        }
        float sn = s[(size_t)atom * F + t] + asv * dot + ass;
        s[(size_t)atom * F + t] = sn;
        s_h[(size_t)atom * F + t] = (_Float16)sn;
    }
}

// ---------------------------------------------------------------- readout, 16 atoms/block, 64 threads
__global__ __launch_bounds__(64) void readout_kernel(
    const float* __restrict__ s, const float* __restrict__ w1T,
    const float* __restrict__ b1,
    const float* __restrict__ w2, const float* __restrict__ b2, float* __restrict__ out) {
    const int TA = 16;
    __shared__ __align__(16) float sh_s[F][20];
    int a0 = blockIdx.x * TA;
    int t = threadIdx.x;
#pragma unroll
    for (int a = 0; a < TA; ++a) {
        int atom = a0 + a;
        sh_s[t][a]      = (atom < N_ATOMS) ? s[atom * F + t] : 0.0f;
        sh_s[t + 64][a] = (atom < N_ATOMS) ? s[atom * F + 64 + t] : 0.0f;
    }
    __syncthreads();
    float acc[TA];
    float bb = b1[t];
#pragma unroll
    for (int a = 0; a < TA; ++a) acc[a] = bb;
    const float* wr = w1T + t * F;
#pragma unroll 2
    for (int k = 0; k < F; k += 4) {
        float4 wq = *(const float4*)(wr + k);
        float wj[4] = {wq.x, wq.y, wq.z, wq.w};
#pragma unroll
        for (int j = 0; j < 4; ++j) {
            const float* rp = &sh_s[k + j][0];
            float4 q0 = *(const float4*)(rp), q1 = *(const float4*)(rp + 4);
            float4 q2 = *(const float4*)(rp + 8), q3 = *(const float4*)(rp + 12);
            float sv[TA] = {q0.x, q0.y, q0.z, q0.w, q1.x, q1.y, q1.z, q1.w,
                            q2.x, q2.y, q2.z, q2.w, q3.x, q3.y, q3.z, q3.w};
#pragma unroll
            for (int a = 0; a < TA; ++a) acc[a] += sv[a] * wj[j];
        }
    }
    float w2t = w2[t];
    float p[TA];
#pragma unroll
    for (int a = 0; a < TA; ++a) p[a] = silu_f(acc[a]) * w2t;
#pragma unroll
    for (int a = 0; a < TA; ++a)
#pragma unroll
        for (int off = 32; off > 0; off >>= 1) p[a] += __shfl_down(p[a], off, 64);
    if (t == 0) {
        float bias = b2[0];
#pragma unroll
        for (int a = 0; a < TA; ++a) {
            int atom = a0 + a;
            if (atom < N_ATOMS) out[atom] = p[a] + bias;
        }
    }
}

extern "C" void kernel_launch(void* const* d_in, const int* in_sizes, int n_in,
                              void* d_out, int out_size, void* d_ws, size_t ws_size,
                              hipStream_t stream) {
    const int*   Z      = (const int*)d_in[0];
    const int*   eidx   = (const int*)d_in[1];
    const float* ediff  = (const float*)d_in[2];
    const float* edist  = (const float*)d_in[3];
    const float* emb    = (const float*)d_in[4];
    const float* msg_w1 = (const float*)d_in[5];
    const float* msg_b1 = (const float*)d_in[6];
    const float* msg_w2 = (const float*)d_in[7];
    const float* msg_b2 = (const float*)d_in[8];
    const float* filt_w = (const float*)d_in[9];
    const float* filt_b = (const float*)d_in[10];
    const float* upd_U  = (const float*)d_in[11];
    const float* upd_V  = (const float*)d_in[12];
    const float* upd_w1 = (const float*)d_in[13];
    const float* upd_b1 = (const float*)d_in[14];
    const float* upd_w2 = (const float*)d_in[15];
    const float* upd_b2 = (const float*)d_in[16];
    const float* ro_w1  = (const float*)d_in[17];
    const float* ro_b1  = (const float*)d_in[18];
    const float* ro_w2  = (const float*)d_in[19];
    const float* ro_b2  = (const float*)d_in[20];
    float* out = (float*)d_out;

    // ---------------- workspace layout ----------------
    float* ws = (float*)d_ws;
    float* s   = ws;                      // N*F f32
    float* v   = s + N_ATOMS * F;         // N*3F f32
    float* roT = v + N_ATOMS * 3 * F;     // 64*F f32
    int* count  = (int*)(roT + 64 * F);   // N
    int* bucket = count + N_ATOMS;        // N*CAP
    _Float16* hbase = (_Float16*)(bucket + N_ATOMS * CAP);
    _Float16* s_h      = hbase;                               // N*F
    _Float16* v_h      = s_h + (size_t)N_ATOMS * F;           // N*3F
    _Float16* vmid_h   = v_h + (size_t)N_ATOMS * 3 * F;       // N*3F
    _Float16* phi_h    = vmid_h + (size_t)N_ATOMS * 3 * F;    // N*3F
    _Float16* concat_h = phi_h + (size_t)N_ATOMS * 3 * F;     // N*2F
    _Float16* UV       = concat_h + (size_t)N_ATOMS * 2 * F;  // (N*3)*2F
    _Float16* wh       = UV + (size_t)N_ATOMS * 3 * 2 * F;    // f16 weights

    const int HWL = 16384 + 49152 + 32768 + 32768 + 49152;    // 180224 halves/layer
    _Float16* mw1T = wh;                  // [128][128]
    _Float16* mw2T = wh + 16384;          // [384][128]
    _Float16* uvT  = wh + 65536;          // [256][128]
    _Float16* uw1T = wh + 98304;          // [128][256]
    _Float16* uw2T = wh + 131072;         // [384][128]

    // ---------------- transpose plan (f16 + f32 merged) ----------------
    TPlansX P; int nb = 0, pi = 0;
    auto add = [&](const float* src, void* dst, int R, int C, int isf16) {
        P.p[pi].src = src; P.p[pi].dst = dst; P.p[pi].R = R; P.p[pi].C = C;
        P.p[pi].blk0 = nb; P.p[pi].isf16 = isf16;
        nb += (R * C + 255) / 256; ++pi;
    };
    for (int l = 0; l < NL; ++l) {
        add(msg_w1 + l * F * F,     mw1T + (size_t)l * HWL, F, F, 1);
        add(msg_w2 + l * F * 3 * F, mw2T + (size_t)l * HWL, F, 3 * F, 1);
        add(upd_U  + l * F * F,     uvT  + (size_t)l * HWL, F, F, 1);
        add(upd_V  + l * F * F,     uvT  + (size_t)l * HWL + F * F, F, F, 1);
        add(upd_w1 + l * 2 * F * F, uw1T + (size_t)l * HWL, 2 * F, F, 1);
        add(upd_w2 + l * F * 3 * F, uw2T + (size_t)l * HWL, F, 3 * F, 1);
    }
    add(ro_w1, roT, F, 64, 0);
    P.n = pi;

    // ---------------- launch ----------------
    init_kernel<<<N_ATOMS, F, 0, stream>>>(Z, emb, s, s_h);
    hipMemsetAsync(v, 0, (size_t)N_ATOMS * 3 * F * sizeof(float), stream);
    hipMemsetAsync(v_h, 0, (size_t)N_ATOMS * 3 * F * sizeof(_Float16), stream);
    hipMemsetAsync(count, 0, (size_t)N_ATOMS * sizeof(int), stream);
    fill_buckets<<<(N_EDGES + 255) / 256, 256, 0, stream>>>(eidx, count, bucket);
    transpose_x<<<nb, 256, 0, stream>>>(P);

    const int GB = (N_ATOMS + 15) / 16;   // 313
    for (int l = 0; l < NL; ++l) {
        phi_mlp_kernel<<<GB, 256, 0, stream>>>(
            s_h, mw1T + (size_t)l * HWL, msg_b1 + l * F,
            mw2T + (size_t)l * HWL, msg_b2 + l * 3 * F, phi_h);
        edge_agg_kernel<<<N_ATOMS, 256, 0, stream>>>(
            count, bucket, eidx, ediff, edist,
            filt_w + l * B * 3 * F, filt_b + l * 3 * F, phi_h, v_h,
            s, v, concat_h, vmid_h);
        uvgemm_vn_kernel<<<GB, 256, 0, stream>>>(
            vmid_h, uvT + (size_t)l * HWL, UV, concat_h);
        upd_mlp_kernel<<<GB, 256, 0, stream>>>(
            concat_h, uw1T + (size_t)l * HWL, upd_b1 + l * F,
            uw2T + (size_t)l * HWL, upd_b2 + l * 3 * F, UV,
            s, v, s_h, v_h);
    }
    readout_kernel<<<GB, 64, 0, stream>>>(s, roT, ro_b1, ro_w2, ro_b2, out);
}

// Round 10
// 455.789 us; speedup vs baseline: 1.9723x; 1.0604x over previous
//
#include <hip/hip_runtime.h>
#include <hip/hip_bf16.h>
#include <hip/hip_fp16.h>
#include <math.h>

#define N_ATOMS 5000
#define N_EDGES 100000
#define F 128
#define B 20
#define NL 3
#define CAP 96

constexpr float CUTOFF = 5.0f;
constexpr float PI_F = 3.14159265358979323846f;

typedef _Float16 f16x8 __attribute__((ext_vector_type(8)));
typedef float f32x4 __attribute__((ext_vector_type(4)));

__device__ __forceinline__ float silu_f(float x) { return x / (1.0f + __expf(-x)); }

// ---------------------------------------------------------------- init: s = emb[Z]; zero v, v_h, count
__global__ void init_kernel(const int* __restrict__ Z, const float* __restrict__ emb,
                            float* __restrict__ s, _Float16* __restrict__ s_h,
                            float* __restrict__ v, _Float16* __restrict__ v_h,
                            int* __restrict__ count) {
    int atom = blockIdx.x;
    int t = threadIdx.x;
    float val = emb[Z[atom] * F + t];
    s[atom * F + t] = val;
    s_h[atom * F + t] = (_Float16)val;
#pragma unroll
    for (int d = 0; d < 3; ++d) {
        v[(size_t)atom * 3 * F + d * F + t] = 0.0f;
        v_h[(size_t)atom * 3 * F + d * F + t] = (_Float16)0.0f;
    }
    if (t == 0) count[atom] = 0;
}

// ---------------------------------------------------------------- bucket edges by dst
__global__ void fill_buckets(const int* __restrict__ eidx, int* __restrict__ count,
                             int* __restrict__ bucket) {
    int e = blockIdx.x * 256 + threadIdx.x;
    if (e >= N_EDGES) return;
    int dst = eidx[2 * e];
    int pos = atomicAdd(&count[dst], 1);
    if (pos < CAP) bucket[dst * CAP + pos] = e;
}

// ---------------------------------------------------------------- transpose (f16 or f32 dst)
struct TPlanX { const float* src; void* dst; int R, C, blk0, isf16; };
struct TPlansX { TPlanX p[20]; int n; };

__global__ void transpose_x(TPlansX P) {
    int b = blockIdx.x;
    int pi = 0;
#pragma unroll
    for (int i = 1; i < 20; ++i)
        if (i < P.n && b >= P.p[i].blk0) pi = i;
    const float* src = P.p[pi].src;
    int R = P.p[pi].R, C = P.p[pi].C;
    int f = (b - P.p[pi].blk0) * 256 + threadIdx.x;
    if (f < R * C) {
        int c = f / R, r = f - c * R;
        float val = src[r * C + c];
        if (P.p[pi].isf16) ((_Float16*)P.p[pi].dst)[f] = (_Float16)val;
        else ((float*)P.p[pi].dst)[f] = val;
    }
}

// ---------------------------------------------------------------- phiMLP: phi = silu(s@W1+b1)@W2+b2
__global__ __launch_bounds__(256) void phi_mlp_kernel(
    const _Float16* __restrict__ s_h, const _Float16* __restrict__ w1T,  // [128][128]
    const float* __restrict__ b1, const _Float16* __restrict__ w2T,      // [384][128]
    const float* __restrict__ b2, _Float16* __restrict__ phi_h) {
    __shared__ __align__(16) _Float16 shA[16 * 136];
    __shared__ __align__(16) _Float16 shH[16 * 136];
    int r0 = blockIdx.x * 16;
    int tid = threadIdx.x;
    {
        int r = tid >> 4, c8 = (tid & 15) * 8;
        int rg = r0 + r; if (rg >= N_ATOMS) rg = N_ATOMS - 1;
        *(f16x8*)(shA + r * 136 + c8) = *(const f16x8*)(s_h + (size_t)rg * F + c8);
    }
    __syncthreads();
    int lane = tid & 63, wv = tid >> 6;
    int col = lane & 15, quad = lane >> 4;
    for (int nt = wv; nt < 8; nt += 4) {
        int n = nt * 16 + col;
        f32x4 acc = {0.f, 0.f, 0.f, 0.f};
#pragma unroll
        for (int kt = 0; kt < 4; ++kt) {
            f16x8 afr = *(const f16x8*)(shA + col * 136 + kt * 32 + quad * 8);
            f16x8 bfr = *(const f16x8*)(w1T + (size_t)n * 128 + kt * 32 + quad * 8);
            acc = __builtin_amdgcn_mfma_f32_16x16x32_f16(afr, bfr, acc, 0, 0, 0);
        }
        float bb = b1[n];
#pragma unroll
        for (int r = 0; r < 4; ++r)
            shH[(quad * 4 + r) * 136 + n] = (_Float16)silu_f(acc[r] + bb);
    }
    __syncthreads();
    for (int nt = wv; nt < 24; nt += 4) {
        int n = nt * 16 + col;
        f32x4 acc = {0.f, 0.f, 0.f, 0.f};
#pragma unroll
        for (int kt = 0; kt < 4; ++kt) {
            f16x8 afr = *(const f16x8*)(shH + col * 136 + kt * 32 + quad * 8);
            f16x8 bfr = *(const f16x8*)(w2T + (size_t)n * 128 + kt * 32 + quad * 8);
            acc = __builtin_amdgcn_mfma_f32_16x16x32_f16(afr, bfr, acc, 0, 0, 0);
        }
        float bb = b2[n];
#pragma unroll
        for (int r = 0; r < 4; ++r) {
            int row = r0 + quad * 4 + r;
            if (row < N_ATOMS) phi_h[(size_t)row * 384 + n] = (_Float16)(acc[r] + bb);
        }
    }
}

// ---------------------------------------------------------------- per-dst edge aggregation
// rbf rows padded to 24 floats (16B-aligned): read per edge as 5x ds_read_b128.
__global__ __launch_bounds__(256) void edge_agg_kernel(
    const int* __restrict__ count, const int* __restrict__ bucket,
    const int* __restrict__ eidx, const float* __restrict__ ediff,
    const float* __restrict__ edist,
    const float* __restrict__ fw, const float* __restrict__ fb,
    const _Float16* __restrict__ phi_h, const _Float16* __restrict__ v_h,
    float* __restrict__ s, float* __restrict__ v,
    _Float16* __restrict__ vmid_h) {
    int a = blockIdx.x;
    int tid = threadIdx.x;
    int t = tid & 127;
    int team = tid >> 7;

    float rfw0[B], rfw1[B], rfw2[B];
#pragma unroll
    for (int b = 0; b < B; ++b) {
        const float* row = fw + b * 3 * F;
        rfw0[b] = row[t]; rfw1[b] = row[F + t]; rfw2[b] = row[2 * F + t];
    }
    float fb0 = fb[t], fb1 = fb[F + t], fb2 = fb[2 * F + t];

    int n = count[a]; if (n > CAP) n = CAP;
    float accS = 0.f, accV0 = 0.f, accV1 = 0.f, accV2 = 0.f;

    __shared__ __align__(16) float sh_rbf[32 * 24];   // row stride 24 (96B, 16B-aligned)
    __shared__ float sh_env[32];
    __shared__ float sh_unit[32][3];
    __shared__ int sh_src[32];
    __shared__ __align__(16) float sh_part[4][F];
    const int* bptr = bucket + a * CAP;

    for (int base = 0; base < n; base += 32) {
        int cnt = min(32, n - base);
        __syncthreads();
        if (tid < cnt) {
            int e = bptr[base + tid];
            sh_src[tid] = eidx[2 * e + 1];
            float d = edist[e];
            float fc = 0.5f * (cosf(PI_F * d / CUTOFF) + 1.0f);
            sh_env[tid] = (d < CUTOFF) ? fc : 0.0f;
            float inv = 1.0f / d;
            sh_unit[tid][0] = ediff[3 * e + 0] * inv;
            sh_unit[tid][1] = ediff[3 * e + 1] * inv;
            sh_unit[tid][2] = ediff[3 * e + 2] * inv;
        }
        for (int task = tid; task < cnt * B; task += 256) {
            int i = task / B, b = task - i * B;
            int e = bptr[base + i];
            float d = edist[e];
            sh_rbf[i * 24 + b] = sinf(d * (float)(b + 1) * (PI_F / CUTOFF)) / d;
        }
        __syncthreads();

        int myCnt = (cnt > team) ? ((cnt - team + 1) >> 1) : 0;
        if (myCnt > 0) {
            _Float16 PA[4][3], VA[4][3], PB[4][3], VB[4][3];
            int ngrp = (myCnt + 3) >> 2;

            auto load_grp = [&](int gbase, _Float16 P[4][3], _Float16 V4[4][3]) {
#pragma unroll
                for (int j = 0; j < 4; ++j) {
                    int i = gbase + j;
                    int ii = (i < myCnt) ? i : (myCnt - 1);
                    int src = sh_src[team + 2 * ii];
                    const _Float16* ps = phi_h + (size_t)src * 3 * F;
                    const _Float16* vs = v_h + (size_t)src * 3 * F;
                    P[j][0] = ps[t]; P[j][1] = ps[F + t]; P[j][2] = ps[2 * F + t];
                    V4[j][0] = vs[t]; V4[j][1] = vs[F + t]; V4[j][2] = vs[2 * F + t];
                }
            };
            auto comp_grp = [&](int gbase, _Float16 P[4][3], _Float16 V4[4][3]) {
#pragma unroll
                for (int j = 0; j < 4; ++j) {
                    int i = gbase + j;
                    if (i < myCnt) {
                        int ei = team + 2 * i;
                        const float4* rp = (const float4*)(sh_rbf + ei * 24);
                        float4 q0 = rp[0], q1 = rp[1], q2 = rp[2], q3 = rp[3], q4 = rp[4];
                        float rr[20] = {q0.x, q0.y, q0.z, q0.w, q1.x, q1.y, q1.z, q1.w,
                                        q2.x, q2.y, q2.z, q2.w, q3.x, q3.y, q3.z, q3.w,
                                        q4.x, q4.y, q4.z, q4.w};
                        float f0 = fb0, f1 = fb1, f2 = fb2;
#pragma unroll
                        for (int b = 0; b < B; ++b) {
                            f0 += rr[b] * rfw0[b]; f1 += rr[b] * rfw1[b]; f2 += rr[b] * rfw2[b];
                        }
                        float env = sh_env[ei];
                        f0 *= env; f1 *= env; f2 *= env;
                        accS += f2 * (float)P[j][2];
                        float gsv = f0 * (float)P[j][0];
                        float gev = f1 * (float)P[j][1];
                        accV0 += (float)V4[j][0] * gsv + gev * sh_unit[ei][0];
                        accV1 += (float)V4[j][1] * gsv + gev * sh_unit[ei][1];
                        accV2 += (float)V4[j][2] * gsv + gev * sh_unit[ei][2];
                    }
                }
            };

            load_grp(0, PA, VA);
            for (int g = 0; g < ngrp; g += 2) {
                if (g + 1 < ngrp) load_grp((g + 1) * 4, PB, VB);
                comp_grp(g * 4, PA, VA);
                if (g + 1 < ngrp) {
                    if (g + 2 < ngrp) load_grp((g + 2) * 4, PA, VA);
                    comp_grp((g + 1) * 4, PB, VB);
                }
            }
        }
    }

    __syncthreads();
    if (team == 1) {
        sh_part[0][t] = accS; sh_part[1][t] = accV0;
        sh_part[2][t] = accV1; sh_part[3][t] = accV2;
    }
    __syncthreads();
    if (team == 0) {
        float sm = s[a * F + t] + accS + sh_part[0][t];
        s[a * F + t] = sm;
        float vm0 = v[a * 3 * F + t] + accV0 + sh_part[1][t];
        float vm1 = v[a * 3 * F + F + t] + accV1 + sh_part[2][t];
        float vm2 = v[a * 3 * F + 2 * F + t] + accV2 + sh_part[3][t];
        v[a * 3 * F + t] = vm0;
        v[a * 3 * F + F + t] = vm1;
        v[a * 3 * F + 2 * F + t] = vm2;
        vmid_h[(size_t)(a * 3 + 0) * F + t] = (_Float16)vm0;
        vmid_h[(size_t)(a * 3 + 1) * F + t] = (_Float16)vm1;
        vmid_h[(size_t)(a * 3 + 2) * F + t] = (_Float16)vm2;
    }
}

// ---------------------------------------------------------------- fused update:
// UV = vmid@[U|V] (LDS-only) -> Vn -> a = silu(concat@w1+b1)@w2+b2 -> final v/s update.
// block = 16 atoms (48 vmid rows), 256 thr.
__global__ __launch_bounds__(256) void fused_update_kernel(
    const _Float16* __restrict__ vmid_h, const _Float16* __restrict__ uvT,  // [256][128]
    const _Float16* __restrict__ w1T,   // [128][256]
    const float* __restrict__ b1, const _Float16* __restrict__ w2T,  // [384][128]
    const float* __restrict__ b2,
    float* __restrict__ s, float* __restrict__ v,
    _Float16* __restrict__ s_h, _Float16* __restrict__ v_h) {
    __shared__ __align__(16) _Float16 shA[48 * 136];    // vmid tile
    __shared__ __align__(16) _Float16 shUV[48 * 264];   // Uv|Vv
    __shared__ __align__(16) _Float16 shCat[16 * 264];  // [s|Vn]
    __shared__ __align__(16) _Float16 shH[16 * 136];    // hidden
    __shared__ __align__(16) _Float16 shAa[16 * 392];   // a-outputs
    int a0 = blockIdx.x * 16;
    int r0 = a0 * 3;
    int tid = threadIdx.x;
    for (int slot = tid; slot < 48 * 16; slot += 256) {
        int r = slot >> 4, c8 = (slot & 15) * 8;
        int rg = r0 + r; if (rg >= N_ATOMS * 3) rg = N_ATOMS * 3 - 1;
        *(f16x8*)(shA + r * 136 + c8) = *(const f16x8*)(vmid_h + (size_t)rg * F + c8);
    }
    __syncthreads();
    int lane = tid & 63, wv = tid >> 6;
    int col = lane & 15, quad = lane >> 4;

    // stage 1: UV tile (48 rows x 256 cols), 12 (mt,nt) tiles per wave
    for (int j = wv; j < 48; j += 4) {
        int mt = j >> 4, nt = j & 15;
        int n = nt * 16 + col;
        f32x4 acc = {0.f, 0.f, 0.f, 0.f};
#pragma unroll
        for (int kt = 0; kt < 4; ++kt) {
            f16x8 afr = *(const f16x8*)(shA + (mt * 16 + col) * 136 + kt * 32 + quad * 8);
            f16x8 bfr = *(const f16x8*)(uvT + (size_t)n * 128 + kt * 32 + quad * 8);
            acc = __builtin_amdgcn_mfma_f32_16x16x32_f16(afr, bfr, acc, 0, 0, 0);
        }
#pragma unroll
        for (int r = 0; r < 4; ++r)
            shUV[(mt * 16 + quad * 4 + r) * 264 + n] = (_Float16)acc[r];
    }
    __syncthreads();

    // stage 2: concat = [s (from f32 global), Vn]
    for (int p = tid; p < 2048; p += 256) {
        int ai = p >> 7, t = p & 127;
        int atom = a0 + ai;
        int ag = (atom < N_ATOMS) ? atom : N_ATOMS - 1;
        shCat[ai * 264 + t] = (_Float16)s[(size_t)ag * F + t];
        float x0 = (float)shUV[(ai * 3 + 0) * 264 + 128 + t];
        float x1 = (float)shUV[(ai * 3 + 1) * 264 + 128 + t];
        float x2 = (float)shUV[(ai * 3 + 2) * 264 + 128 + t];
        shCat[ai * 264 + 128 + t] = (_Float16)sqrtf(x0 * x0 + x1 * x1 + x2 * x2);
    }
    __syncthreads();

    // stage 3: hidden = silu(concat @ w1 + b1), K=256
    for (int nt = wv; nt < 8; nt += 4) {
        int n = nt * 16 + col;
        f32x4 acc = {0.f, 0.f, 0.f, 0.f};
#pragma unroll
        for (int kt = 0; kt < 8; ++kt) {
            f16x8 afr = *(const f16x8*)(shCat + col * 264 + kt * 32 + quad * 8);
            f16x8 bfr = *(const f16x8*)(w1T + (size_t)n * 256 + kt * 32 + quad * 8);
            acc = __builtin_amdgcn_mfma_f32_16x16x32_f16(afr, bfr, acc, 0, 0, 0);
        }
        float bb = b1[n];
#pragma unroll
        for (int r = 0; r < 4; ++r)
            shH[(quad * 4 + r) * 136 + n] = (_Float16)silu_f(acc[r] + bb);
    }
    __syncthreads();

    // stage 4: a = hidden @ w2 + b2
    for (int nt = wv; nt < 24; nt += 4) {
        int n = nt * 16 + col;
        f32x4 acc = {0.f, 0.f, 0.f, 0.f};
#pragma unroll
        for (int kt = 0; kt < 4; ++kt) {
            f16x8 afr = *(const f16x8*)(shH + col * 136 + kt * 32 + quad * 8);
            f16x8 bfr = *(const f16x8*)(w2T + (size_t)n * 128 + kt * 32 + quad * 8);
            acc = __builtin_amdgcn_mfma_f32_16x16x32_f16(afr, bfr, acc, 0, 0, 0);
        }
        float bb = b2[n];
#pragma unroll
        for (int r = 0; r < 4; ++r)
            shAa[(quad * 4 + r) * 392 + n] = (_Float16)(acc[r] + bb);
    }
    __syncthreads();

    // stage 5: final elementwise update
    for (int p = tid; p < 2048; p += 256) {
        int ai = p >> 7, t = p & 127;
        int atom = a0 + ai;
        if (atom >= N_ATOMS) break;
        float avv = (float)shAa[ai * 392 + t];
        float asv = (float)shAa[ai * 392 + 128 + t];
        float ass = (float)shAa[ai * 392 + 256 + t];
        float dot = 0.f;
#pragma unroll
        for (int d = 0; d < 3; ++d) {
            float u = (float)shUV[(ai * 3 + d) * 264 + t];
            float w = (float)shUV[(ai * 3 + d) * 264 + 128 + t];
            dot += u * w;
            float nv = v[(size_t)atom * 3 * F + d * F + t] + avv * u;
            v[(size_t)atom * 3 * F + d * F + t] = nv;
            v_h[(size_t)atom * 3 * F + d * F + t] = (_Float16)nv;
        }
        float sn = s[(size_t)atom * F + t] + asv * dot + ass;
        s[(size_t)atom * F + t] = sn;
        s_h[(size_t)atom * F + t] = (_Float16)sn;
    }
}

// ---------------------------------------------------------------- readout, 16 atoms/block, 64 threads
__global__ __launch_bounds__(64) void readout_kernel(
    const float* __restrict__ s, const float* __restrict__ w1T,
    const float* __restrict__ b1,
    const float* __restrict__ w2, const float* __restrict__ b2, float* __restrict__ out) {
    const int TA = 16;
    __shared__ __align__(16) float sh_s[F][20];
    int a0 = blockIdx.x * TA;
    int t = threadIdx.x;
#pragma unroll
    for (int a = 0; a < TA; ++a) {
        int atom = a0 + a;
        sh_s[t][a]      = (atom < N_ATOMS) ? s[atom * F + t] : 0.0f;
        sh_s[t + 64][a] = (atom < N_ATOMS) ? s[atom * F + 64 + t] : 0.0f;
    }
    __syncthreads();
    float acc[TA];
    float bb = b1[t];
#pragma unroll
    for (int a = 0; a < TA; ++a) acc[a] = bb;
    const float* wr = w1T + t * F;
#pragma unroll 2
    for (int k = 0; k < F; k += 4) {
        float4 wq = *(const float4*)(wr + k);
        float wj[4] = {wq.x, wq.y, wq.z, wq.w};
#pragma unroll
        for (int j = 0; j < 4; ++j) {
            const float* rp = &sh_s[k + j][0];
            float4 q0 = *(const float4*)(rp), q1 = *(const float4*)(rp + 4);
            float4 q2 = *(const float4*)(rp + 8), q3 = *(const float4*)(rp + 12);
            float sv[TA] = {q0.x, q0.y, q0.z, q0.w, q1.x, q1.y, q1.z, q1.w,
                            q2.x, q2.y, q2.z, q2.w, q3.x, q3.y, q3.z, q3.w};
#pragma unroll
            for (int a = 0; a < TA; ++a) acc[a] += sv[a] * wj[j];
        }
    }
    float w2t = w2[t];
    float p[TA];
#pragma unroll
    for (int a = 0; a < TA; ++a) p[a] = silu_f(acc[a]) * w2t;
#pragma unroll
    for (int a = 0; a < TA; ++a)
#pragma unroll
        for (int off = 32; off > 0; off >>= 1) p[a] += __shfl_down(p[a], off, 64);
    if (t == 0) {
        float bias = b2[0];
#pragma unroll
        for (int a = 0; a < TA; ++a) {
            int atom = a0 + a;
            if (atom < N_ATOMS) out[atom] = p[a] + bias;
        }
    }
}

extern "C" void kernel_launch(void* const* d_in, const int* in_sizes, int n_in,
                              void* d_out, int out_size, void* d_ws, size_t ws_size,
                              hipStream_t stream) {
    const int*   Z      = (const int*)d_in[0];
    const int*   eidx   = (const int*)d_in[1];
    const float* ediff  = (const float*)d_in[2];
    const float* edist  = (const float*)d_in[3];
    const float* emb    = (const float*)d_in[4];
    const float* msg_w1 = (const float*)d_in[5];
    const float* msg_b1 = (const float*)d_in[6];
    const float* msg_w2 = (const float*)d_in[7];
    const float* msg_b2 = (const float*)d_in[8];
    const float* filt_w = (const float*)d_in[9];
    const float* filt_b = (const float*)d_in[10];
    const float* upd_U  = (const float*)d_in[11];
    const float* upd_V  = (const float*)d_in[12];
    const float* upd_w1 = (const float*)d_in[13];
    const float* upd_b1 = (const float*)d_in[14];
    const float* upd_w2 = (const float*)d_in[15];
    const float* upd_b2 = (const float*)d_in[16];
    const float* ro_w1  = (const float*)d_in[17];
    const float* ro_b1  = (const float*)d_in[18];
    const float* ro_w2  = (const float*)d_in[19];
    const float* ro_b2  = (const float*)d_in[20];
    float* out = (float*)d_out;

    // ---------------- workspace layout ----------------
    float* ws = (float*)d_ws;
    float* s   = ws;                      // N*F f32
    float* v   = s + N_ATOMS * F;         // N*3F f32
    float* roT = v + N_ATOMS * 3 * F;     // 64*F f32
    int* count  = (int*)(roT + 64 * F);   // N
    int* bucket = count + N_ATOMS;        // N*CAP
    _Float16* hbase = (_Float16*)(bucket + N_ATOMS * CAP);
    _Float16* s_h    = hbase;                               // N*F
    _Float16* v_h    = s_h + (size_t)N_ATOMS * F;           // N*3F
    _Float16* vmid_h = v_h + (size_t)N_ATOMS * 3 * F;       // N*3F
    _Float16* phi_h  = vmid_h + (size_t)N_ATOMS * 3 * F;    // N*3F
    _Float16* wh     = phi_h + (size_t)N_ATOMS * 3 * F;     // f16 weights

    const int HWL = 16384 + 49152 + 32768 + 32768 + 49152;  // 180224 halves/layer
    _Float16* mw1T = wh;                  // [128][128]
    _Float16* mw2T = wh + 16384;          // [384][128]
    _Float16* uvT  = wh + 65536;          // [256][128]
    _Float16* uw1T = wh + 98304;          // [128][256]
    _Float16* uw2T = wh + 131072;         // [384][128]

    // ---------------- transpose plan ----------------
    TPlansX P; int nb = 0, pi = 0;
    auto add = [&](const float* src, void* dst, int R, int C, int isf16) {
        P.p[pi].src = src; P.p[pi].dst = dst; P.p[pi].R = R; P.p[pi].C = C;
        P.p[pi].blk0 = nb; P.p[pi].isf16 = isf16;
        nb += (R * C + 255) / 256; ++pi;
    };
    for (int l = 0; l < NL; ++l) {
        add(msg_w1 + l * F * F,     mw1T + (size_t)l * HWL, F, F, 1);
        add(msg_w2 + l * F * 3 * F, mw2T + (size_t)l * HWL, F, 3 * F, 1);
        add(upd_U  + l * F * F,     uvT  + (size_t)l * HWL, F, F, 1);
        add(upd_V  + l * F * F,     uvT  + (size_t)l * HWL + F * F, F, F, 1);
        add(upd_w1 + l * 2 * F * F, uw1T + (size_t)l * HWL, 2 * F, F, 1);
        add(upd_w2 + l * F * 3 * F, uw2T + (size_t)l * HWL, F, 3 * F, 1);
    }
    add(ro_w1, roT, F, 64, 0);
    P.n = pi;

    // ---------------- launch ----------------
    init_kernel<<<N_ATOMS, F, 0, stream>>>(Z, emb, s, s_h, v, v_h, count);
    fill_buckets<<<(N_EDGES + 255) / 256, 256, 0, stream>>>(eidx, count, bucket);
    transpose_x<<<nb, 256, 0, stream>>>(P);

    const int GB = (N_ATOMS + 15) / 16;   // 313
    for (int l = 0; l < NL; ++l) {
        phi_mlp_kernel<<<GB, 256, 0, stream>>>(
            s_h, mw1T + (size_t)l * HWL, msg_b1 + l * F,
            mw2T + (size_t)l * HWL, msg_b2 + l * 3 * F, phi_h);
        edge_agg_kernel<<<N_ATOMS, 256, 0, stream>>>(
            count, bucket, eidx, ediff, edist,
            filt_w + l * B * 3 * F, filt_b + l * 3 * F, phi_h, v_h,
            s, v, vmid_h);
        fused_update_kernel<<<GB, 256, 0, stream>>>(
            vmid_h, uvT + (size_t)l * HWL,
            uw1T + (size_t)l * HWL, upd_b1 + l * F,
            uw2T + (size_t)l * HWL, upd_b2 + l * 3 * F,
            s, v, s_h, v_h);
    }
    readout_kernel<<<GB, 64, 0, stream>>>(s, roT, ro_b1, ro_w2, ro_b2, out);
}

// Round 11
// 386.394 us; speedup vs baseline: 2.3266x; 1.1796x over previous
//
#include <hip/hip_runtime.h>
#include <hip/hip_bf16.h>
#include <hip/hip_fp16.h>
#include <math.h>

#define N_ATOMS 5000
#define N_EDGES 100000
#define F 128
#define B 20
#define NL 3
#define CAP 64

constexpr float CUTOFF = 5.0f;
constexpr float PI_F = 3.14159265358979323846f;

typedef _Float16 f16x8 __attribute__((ext_vector_type(8)));
typedef _Float16 h2 __attribute__((ext_vector_type(2)));
typedef float f32x4 __attribute__((ext_vector_type(4)));

struct EMeta { int src; float env; float u0, u1, u2; int pad[3]; };  // 32 B

__device__ __forceinline__ float silu_f(float x) { return x / (1.0f + __expf(-x)); }

// ---------------------------------------------------------------- init: s = emb[Z]; zero v, v_h, count
__global__ void init_kernel(const int* __restrict__ Z, const float* __restrict__ emb,
                            float* __restrict__ s, _Float16* __restrict__ s_h,
                            float* __restrict__ v, _Float16* __restrict__ v_h,
                            int* __restrict__ count) {
    int atom = blockIdx.x;
    int t = threadIdx.x;
    float val = emb[Z[atom] * F + t];
    s[atom * F + t] = val;
    s_h[atom * F + t] = (_Float16)val;
#pragma unroll
    for (int d = 0; d < 3; ++d) {
        v[(size_t)atom * 3 * F + d * F + t] = 0.0f;
        v_h[(size_t)atom * 3 * F + d * F + t] = (_Float16)0.0f;
    }
    if (t == 0) count[atom] = 0;
}

// ---------------------------------------------------------------- bucket edges by dst
__global__ void fill_buckets(const int* __restrict__ eidx, int* __restrict__ count,
                             int* __restrict__ bucket) {
    int e = blockIdx.x * 256 + threadIdx.x;
    if (e >= N_EDGES) return;
    int dst = eidx[2 * e];
    int pos = atomicAdd(&count[dst], 1);
    if (pos < CAP) bucket[dst * CAP + pos] = e;
}

// ---------------------------------------------------------------- per-slot edge metadata (layer-invariant)
__global__ void edge_meta_kernel(const int* __restrict__ count, const int* __restrict__ bucket,
                                 const int* __restrict__ eidx, const float* __restrict__ ediff,
                                 const float* __restrict__ edist,
                                 EMeta* __restrict__ meta, _Float16* __restrict__ rbfh) {
    int slot = blockIdx.x * 256 + threadIdx.x;
    if (slot >= N_ATOMS * CAP) return;
    int a = slot / CAP, i = slot % CAP;
    if (i >= count[a]) return;
    int e = bucket[slot];
    float d = edist[e];
    EMeta m;
    m.src = eidx[2 * e + 1];
    float fc = 0.5f * (cosf(PI_F * d / CUTOFF) + 1.0f);
    m.env = (d < CUTOFF) ? fc : 0.0f;
    float inv = 1.0f / d;
    m.u0 = ediff[3 * e + 0] * inv;
    m.u1 = ediff[3 * e + 1] * inv;
    m.u2 = ediff[3 * e + 2] * inv;
    m.pad[0] = m.pad[1] = m.pad[2] = 0;
    meta[slot] = m;
    _Float16* rp = rbfh + (size_t)slot * 24;
#pragma unroll
    for (int b = 0; b < B; ++b)
        rp[b] = (_Float16)(sinf(d * (float)(b + 1) * (PI_F / CUTOFF)) / d);
    rp[20] = rp[21] = rp[22] = rp[23] = (_Float16)0.0f;
}

// ---------------------------------------------------------------- transpose (f16/f32, padded rows)
struct TPlanX { const float* src; void* dst; int R, C, blk0, isf16, pad; };
struct TPlansX { TPlanX p[24]; int n; };

__global__ void transpose_x(TPlansX P) {
    int b = blockIdx.x;
    int pi = 0;
#pragma unroll
    for (int i = 1; i < 24; ++i)
        if (i < P.n && b >= P.p[i].blk0) pi = i;
    const float* src = P.p[pi].src;
    int R = P.p[pi].R, C = P.p[pi].C, pad = P.p[pi].pad;
    int f = (b - P.p[pi].blk0) * 256 + threadIdx.x;
    if (f < R * C) {
        int c = f / R, r = f - c * R;
        float val = src[r * C + c];
        if (P.p[pi].isf16) ((_Float16*)P.p[pi].dst)[c * pad + r] = (_Float16)val;
        else ((float*)P.p[pi].dst)[c * pad + r] = val;
    }
}

// ---------------------------------------------------------------- phiMLP (layer 0 only)
__global__ __launch_bounds__(256) void phi_mlp_kernel(
    const _Float16* __restrict__ s_h, const _Float16* __restrict__ w1T,
    const float* __restrict__ b1, const _Float16* __restrict__ w2T,
    const float* __restrict__ b2, _Float16* __restrict__ phi_h) {
    __shared__ __align__(16) _Float16 shA[16 * 136];
    __shared__ __align__(16) _Float16 shH[16 * 136];
    int r0 = blockIdx.x * 16;
    int tid = threadIdx.x;
    {
        int r = tid >> 4, c8 = (tid & 15) * 8;
        int rg = r0 + r; if (rg >= N_ATOMS) rg = N_ATOMS - 1;
        *(f16x8*)(shA + r * 136 + c8) = *(const f16x8*)(s_h + (size_t)rg * F + c8);
    }
    __syncthreads();
    int lane = tid & 63, wv = tid >> 6;
    int col = lane & 15, quad = lane >> 4;
    for (int nt = wv; nt < 8; nt += 4) {
        int n = nt * 16 + col;
        f32x4 acc = {0.f, 0.f, 0.f, 0.f};
#pragma unroll
        for (int kt = 0; kt < 4; ++kt) {
            f16x8 afr = *(const f16x8*)(shA + col * 136 + kt * 32 + quad * 8);
            f16x8 bfr = *(const f16x8*)(w1T + (size_t)n * 128 + kt * 32 + quad * 8);
            acc = __builtin_amdgcn_mfma_f32_16x16x32_f16(afr, bfr, acc, 0, 0, 0);
        }
        float bb = b1[n];
#pragma unroll
        for (int r = 0; r < 4; ++r)
            shH[(quad * 4 + r) * 136 + n] = (_Float16)silu_f(acc[r] + bb);
    }
    __syncthreads();
    for (int nt = wv; nt < 24; nt += 4) {
        int n = nt * 16 + col;
        f32x4 acc = {0.f, 0.f, 0.f, 0.f};
#pragma unroll
        for (int kt = 0; kt < 4; ++kt) {
            f16x8 afr = *(const f16x8*)(shH + col * 136 + kt * 32 + quad * 8);
            f16x8 bfr = *(const f16x8*)(w2T + (size_t)n * 128 + kt * 32 + quad * 8);
            acc = __builtin_amdgcn_mfma_f32_16x16x32_f16(afr, bfr, acc, 0, 0, 0);
        }
        float bb = b2[n];
#pragma unroll
        for (int r = 0; r < 4; ++r) {
            int row = r0 + quad * 4 + r;
            if (row < N_ATOMS) phi_h[(size_t)row * 384 + n] = (_Float16)(acc[r] + bb);
        }
    }
}

// ---------------------------------------------------------------- per-dst edge aggregation
// metadata precomputed; filter via v_dot2_f32_f16 (f16 rbf x f16 filt_w pairs).
__global__ __launch_bounds__(256) void edge_agg_kernel(
    const int* __restrict__ count, const EMeta* __restrict__ meta,
    const _Float16* __restrict__ rbfh,
    const _Float16* __restrict__ fwT,   // [384][24] f16
    const float* __restrict__ fb,
    const _Float16* __restrict__ phi_h, const _Float16* __restrict__ v_h,
    float* __restrict__ s, float* __restrict__ v,
    _Float16* __restrict__ vmid_h) {
    int a = blockIdx.x;
    int tid = threadIdx.x;
    int t = tid & 127;
    int team = tid >> 7;

    // packed filter-weight pairs for this thread's 3 output columns
    unsigned int rw0[10], rw1[10], rw2[10];
    {
        const unsigned int* p0 = (const unsigned int*)(fwT + (size_t)t * 24);
        const unsigned int* p1 = (const unsigned int*)(fwT + (size_t)(F + t) * 24);
        const unsigned int* p2 = (const unsigned int*)(fwT + (size_t)(2 * F + t) * 24);
#pragma unroll
        for (int j = 0; j < 10; ++j) { rw0[j] = p0[j]; rw1[j] = p1[j]; rw2[j] = p2[j]; }
    }
    float fb0 = fb[t], fb1 = fb[F + t], fb2 = fb[2 * F + t];

    int n = count[a]; if (n > CAP) n = CAP;
    float accS = 0.f, accV0 = 0.f, accV1 = 0.f, accV2 = 0.f;

    __shared__ int sh_src[32];
    __shared__ float sh_env[32];
    __shared__ float sh_unit[32][3];
    __shared__ __align__(16) unsigned int sh_rbf[32 * 12];
    __shared__ __align__(16) float sh_part[4][F];
    const size_t aC = (size_t)a * CAP;
    const unsigned int* rbf32 = (const unsigned int*)rbfh;

    for (int base = 0; base < n; base += 32) {
        int cnt = min(32, n - base);
        __syncthreads();
        if (tid < cnt) {
            EMeta m = meta[aC + base + tid];
            sh_src[tid] = m.src;
            sh_env[tid] = m.env;
            sh_unit[tid][0] = m.u0; sh_unit[tid][1] = m.u1; sh_unit[tid][2] = m.u2;
        }
        for (int task = tid; task < cnt * 12; task += 256) {
            int i = task / 12, w = task - i * 12;
            sh_rbf[i * 12 + w] = rbf32[(aC + base + i) * 12 + w];
        }
        __syncthreads();

        int myCnt = (cnt > team) ? ((cnt - team + 1) >> 1) : 0;
        if (myCnt > 0) {
            _Float16 PA[4][3], VA[4][3], PB[4][3], VB[4][3];
            int ngrp = (myCnt + 3) >> 2;

            auto load_grp = [&](int gbase, _Float16 P[4][3], _Float16 V4[4][3]) {
#pragma unroll
                for (int j = 0; j < 4; ++j) {
                    int i = gbase + j;
                    int ii = (i < myCnt) ? i : (myCnt - 1);
                    int src = sh_src[team + 2 * ii];
                    const _Float16* ps = phi_h + (size_t)src * 3 * F;
                    const _Float16* vs = v_h + (size_t)src * 3 * F;
                    P[j][0] = ps[t]; P[j][1] = ps[F + t]; P[j][2] = ps[2 * F + t];
                    V4[j][0] = vs[t]; V4[j][1] = vs[F + t]; V4[j][2] = vs[2 * F + t];
                }
            };
            auto comp_grp = [&](int gbase, _Float16 P[4][3], _Float16 V4[4][3]) {
#pragma unroll
                for (int j = 0; j < 4; ++j) {
                    int i = gbase + j;
                    if (i < myCnt) {
                        int ei = team + 2 * i;
                        const uint4* rq = (const uint4*)(sh_rbf + ei * 12);
                        uint4 qa = rq[0], qb = rq[1];
                        uint2 qc = *(const uint2*)(sh_rbf + ei * 12 + 8);
                        unsigned int rr[10] = {qa.x, qa.y, qa.z, qa.w,
                                               qb.x, qb.y, qb.z, qb.w, qc.x, qc.y};
                        float f0 = fb0, f1 = fb1, f2 = fb2;
#pragma unroll
                        for (int p = 0; p < 10; ++p) {
                            h2 rb = __builtin_bit_cast(h2, rr[p]);
                            f0 = __builtin_amdgcn_fdot2(rb, __builtin_bit_cast(h2, rw0[p]), f0, false);
                            f1 = __builtin_amdgcn_fdot2(rb, __builtin_bit_cast(h2, rw1[p]), f1, false);
                            f2 = __builtin_amdgcn_fdot2(rb, __builtin_bit_cast(h2, rw2[p]), f2, false);
                        }
                        float env = sh_env[ei];
                        f0 *= env; f1 *= env; f2 *= env;
                        accS += f2 * (float)P[j][2];
                        float gsv = f0 * (float)P[j][0];
                        float gev = f1 * (float)P[j][1];
                        accV0 += (float)V4[j][0] * gsv + gev * sh_unit[ei][0];
                        accV1 += (float)V4[j][1] * gsv + gev * sh_unit[ei][1];
                        accV2 += (float)V4[j][2] * gsv + gev * sh_unit[ei][2];
                    }
                }
            };

            load_grp(0, PA, VA);
            for (int g = 0; g < ngrp; g += 2) {
                if (g + 1 < ngrp) load_grp((g + 1) * 4, PB, VB);
                comp_grp(g * 4, PA, VA);
                if (g + 1 < ngrp) {
                    if (g + 2 < ngrp) load_grp((g + 2) * 4, PA, VA);
                    comp_grp((g + 1) * 4, PB, VB);
                }
            }
        }
    }

    __syncthreads();
    if (team == 1) {
        sh_part[0][t] = accS; sh_part[1][t] = accV0;
        sh_part[2][t] = accV1; sh_part[3][t] = accV2;
    }
    __syncthreads();
    if (team == 0) {
        float sm = s[a * F + t] + accS + sh_part[0][t];
        s[a * F + t] = sm;
        float vm0 = v[a * 3 * F + t] + accV0 + sh_part[1][t];
        float vm1 = v[a * 3 * F + F + t] + accV1 + sh_part[2][t];
        float vm2 = v[a * 3 * F + 2 * F + t] + accV2 + sh_part[3][t];
        v[a * 3 * F + t] = vm0;
        v[a * 3 * F + F + t] = vm1;
        v[a * 3 * F + 2 * F + t] = vm2;
        vmid_h[(size_t)(a * 3 + 0) * F + t] = (_Float16)vm0;
        vmid_h[(size_t)(a * 3 + 1) * F + t] = (_Float16)vm1;
        vmid_h[(size_t)(a * 3 + 2) * F + t] = (_Float16)vm2;
    }
}

// ---------------------------------------------------------------- fused update (+ next layer's phi)
__global__ __launch_bounds__(256) void fused_update_kernel(
    const _Float16* __restrict__ vmid_h, const _Float16* __restrict__ uvT,
    const _Float16* __restrict__ w1T, const float* __restrict__ b1,
    const _Float16* __restrict__ w2T, const float* __restrict__ b2,
    float* __restrict__ s, float* __restrict__ v,
    _Float16* __restrict__ s_h, _Float16* __restrict__ v_h,
    const _Float16* __restrict__ nw1T, const float* __restrict__ nb1,
    const _Float16* __restrict__ nw2T, const float* __restrict__ nb2,
    _Float16* __restrict__ phi_h, int do_phi) {
    __shared__ __align__(16) _Float16 shA[48 * 136];    // vmid tile; reused as s-tile (shS)
    __shared__ __align__(16) _Float16 shUV[48 * 264];
    __shared__ __align__(16) _Float16 shCat[16 * 264];
    __shared__ __align__(16) _Float16 shH[16 * 136];
    __shared__ __align__(16) _Float16 shAa[16 * 392];
    _Float16* shS = shA;
    int a0 = blockIdx.x * 16;
    int r0 = a0 * 3;
    int tid = threadIdx.x;
    for (int slot = tid; slot < 48 * 16; slot += 256) {
        int r = slot >> 4, c8 = (slot & 15) * 8;
        int rg = r0 + r; if (rg >= N_ATOMS * 3) rg = N_ATOMS * 3 - 1;
        *(f16x8*)(shA + r * 136 + c8) = *(const f16x8*)(vmid_h + (size_t)rg * F + c8);
    }
    __syncthreads();
    int lane = tid & 63, wv = tid >> 6;
    int col = lane & 15, quad = lane >> 4;

    // stage 1: UV = vmid @ [U|V]
    for (int j = wv; j < 48; j += 4) {
        int mt = j >> 4, nt = j & 15;
        int n = nt * 16 + col;
        f32x4 acc = {0.f, 0.f, 0.f, 0.f};
#pragma unroll
        for (int kt = 0; kt < 4; ++kt) {
            f16x8 afr = *(const f16x8*)(shA + (mt * 16 + col) * 136 + kt * 32 + quad * 8);
            f16x8 bfr = *(const f16x8*)(uvT + (size_t)n * 128 + kt * 32 + quad * 8);
            acc = __builtin_amdgcn_mfma_f32_16x16x32_f16(afr, bfr, acc, 0, 0, 0);
        }
#pragma unroll
        for (int r = 0; r < 4; ++r)
            shUV[(mt * 16 + quad * 4 + r) * 264 + n] = (_Float16)acc[r];
    }
    __syncthreads();

    // stage 2: concat = [s, Vn]
    for (int p = tid; p < 2048; p += 256) {
        int ai = p >> 7, t = p & 127;
        int atom = a0 + ai;
        int ag = (atom < N_ATOMS) ? atom : N_ATOMS - 1;
        shCat[ai * 264 + t] = (_Float16)s[(size_t)ag * F + t];
        float x0 = (float)shUV[(ai * 3 + 0) * 264 + 128 + t];
        float x1 = (float)shUV[(ai * 3 + 1) * 264 + 128 + t];
        float x2 = (float)shUV[(ai * 3 + 2) * 264 + 128 + t];
        shCat[ai * 264 + 128 + t] = (_Float16)sqrtf(x0 * x0 + x1 * x1 + x2 * x2);
    }
    __syncthreads();

    // stage 3: hidden = silu(concat @ w1 + b1), K=256
    for (int nt = wv; nt < 8; nt += 4) {
        int n = nt * 16 + col;
        f32x4 acc = {0.f, 0.f, 0.f, 0.f};
#pragma unroll
        for (int kt = 0; kt < 8; ++kt) {
            f16x8 afr = *(const f16x8*)(shCat + col * 264 + kt * 32 + quad * 8);
            f16x8 bfr = *(const f16x8*)(w1T + (size_t)n * 256 + kt * 32 + quad * 8);
            acc = __builtin_amdgcn_mfma_f32_16x16x32_f16(afr, bfr, acc, 0, 0, 0);
        }
        float bb = b1[n];
#pragma unroll
        for (int r = 0; r < 4; ++r)
            shH[(quad * 4 + r) * 136 + n] = (_Float16)silu_f(acc[r] + bb);
    }
    __syncthreads();

    // stage 4: a = hidden @ w2 + b2
    for (int nt = wv; nt < 24; nt += 4) {
        int n = nt * 16 + col;
        f32x4 acc = {0.f, 0.f, 0.f, 0.f};
#pragma unroll
        for (int kt = 0; kt < 4; ++kt) {
            f16x8 afr = *(const f16x8*)(shH + col * 136 + kt * 32 + quad * 8);
            f16x8 bfr = *(const f16x8*)(w2T + (size_t)n * 128 + kt * 32 + quad * 8);
            acc = __builtin_amdgcn_mfma_f32_16x16x32_f16(afr, bfr, acc, 0, 0, 0);
        }
        float bb = b2[n];
#pragma unroll
        for (int r = 0; r < 4; ++r)
            shAa[(quad * 4 + r) * 392 + n] = (_Float16)(acc[r] + bb);
    }
    __syncthreads();

    // stage 5: final elementwise update; stash new s in shS (f16)
    for (int p = tid; p < 2048; p += 256) {
        int ai = p >> 7, t = p & 127;
        int atom = a0 + ai;
        if (atom >= N_ATOMS) { shS[ai * 136 + t] = (_Float16)0.0f; continue; }
        float avv = (float)shAa[ai * 392 + t];
        float asv = (float)shAa[ai * 392 + 128 + t];
        float ass = (float)shAa[ai * 392 + 256 + t];
        float dot = 0.f;
#pragma unroll
        for (int d = 0; d < 3; ++d) {
            float u = (float)shUV[(ai * 3 + d) * 264 + t];
            float w = (float)shUV[(ai * 3 + d) * 264 + 128 + t];
            dot += u * w;
            float nv = v[(size_t)atom * 3 * F + d * F + t] + avv * u;
            v[(size_t)atom * 3 * F + d * F + t] = nv;
            v_h[(size_t)atom * 3 * F + d * F + t] = (_Float16)nv;
        }
        float sn = s[(size_t)atom * F + t] + asv * dot + ass;
        s[(size_t)atom * F + t] = sn;
        s_h[(size_t)atom * F + t] = (_Float16)sn;
        shS[ai * 136 + t] = (_Float16)sn;
    }

    // stage 6: next layer's phi = silu(s_new @ nw1 + nb1) @ nw2 + nb2
    if (do_phi) {
        __syncthreads();
        for (int nt = wv; nt < 8; nt += 4) {
            int n = nt * 16 + col;
            f32x4 acc = {0.f, 0.f, 0.f, 0.f};
#pragma unroll
            for (int kt = 0; kt < 4; ++kt) {
                f16x8 afr = *(const f16x8*)(shS + col * 136 + kt * 32 + quad * 8);
                f16x8 bfr = *(const f16x8*)(nw1T + (size_t)n * 128 + kt * 32 + quad * 8);
                acc = __builtin_amdgcn_mfma_f32_16x16x32_f16(afr, bfr, acc, 0, 0, 0);
            }
            float bb = nb1[n];
#pragma unroll
            for (int r = 0; r < 4; ++r)
                shH[(quad * 4 + r) * 136 + n] = (_Float16)silu_f(acc[r] + bb);
        }
        __syncthreads();
        for (int nt = wv; nt < 24; nt += 4) {
            int n = nt * 16 + col;
            f32x4 acc = {0.f, 0.f, 0.f, 0.f};
#pragma unroll
            for (int kt = 0; kt < 4; ++kt) {
                f16x8 afr = *(const f16x8*)(shH + col * 136 + kt * 32 + quad * 8);
                f16x8 bfr = *(const f16x8*)(nw2T + (size_t)n * 128 + kt * 32 + quad * 8);
                acc = __builtin_amdgcn_mfma_f32_16x16x32_f16(afr, bfr, acc, 0, 0, 0);
            }
            float bb = nb2[n];
#pragma unroll
            for (int r = 0; r < 4; ++r) {
                int row = a0 + quad * 4 + r;
                if (row < N_ATOMS) phi_h[(size_t)row * 384 + n] = (_Float16)(acc[r] + bb);
            }
        }
    }
}

// ---------------------------------------------------------------- readout
__global__ __launch_bounds__(64) void readout_kernel(
    const float* __restrict__ s, const float* __restrict__ w1T,
    const float* __restrict__ b1,
    const float* __restrict__ w2, const float* __restrict__ b2, float* __restrict__ out) {
    const int TA = 16;
    __shared__ __align__(16) float sh_s[F][20];
    int a0 = blockIdx.x * TA;
    int t = threadIdx.x;
#pragma unroll
    for (int a = 0; a < TA; ++a) {
        int atom = a0 + a;
        sh_s[t][a]      = (atom < N_ATOMS) ? s[atom * F + t] : 0.0f;
        sh_s[t + 64][a] = (atom < N_ATOMS) ? s[atom * F + 64 + t] : 0.0f;
    }
    __syncthreads();
    float acc[TA];
    float bb = b1[t];
#pragma unroll
    for (int a = 0; a < TA; ++a) acc[a] = bb;
    const float* wr = w1T + t * F;
#pragma unroll 2
    for (int k = 0; k < F; k += 4) {
        float4 wq = *(const float4*)(wr + k);
        float wj[4] = {wq.x, wq.y, wq.z, wq.w};
#pragma unroll
        for (int j = 0; j < 4; ++j) {
            const float* rp = &sh_s[k + j][0];
            float4 q0 = *(const float4*)(rp), q1 = *(const float4*)(rp + 4);
            float4 q2 = *(const float4*)(rp + 8), q3 = *(const float4*)(rp + 12);
            float sv[TA] = {q0.x, q0.y, q0.z, q0.w, q1.x, q1.y, q1.z, q1.w,
                            q2.x, q2.y, q2.z, q2.w, q3.x, q3.y, q3.z, q3.w};
#pragma unroll
            for (int a = 0; a < TA; ++a) acc[a] += sv[a] * wj[j];
        }
    }
    float w2t = w2[t];
    float p[TA];
#pragma unroll
    for (int a = 0; a < TA; ++a) p[a] = silu_f(acc[a]) * w2t;
#pragma unroll
    for (int a = 0; a < TA; ++a)
#pragma unroll
        for (int off = 32; off > 0; off >>= 1) p[a] += __shfl_down(p[a], off, 64);
    if (t == 0) {
        float bias = b2[0];
#pragma unroll
        for (int a = 0; a < TA; ++a) {
            int atom = a0 + a;
            if (atom < N_ATOMS) out[atom] = p[a] + bias;
        }
    }
}

extern "C" void kernel_launch(void* const* d_in, const int* in_sizes, int n_in,
                              void* d_out, int out_size, void* d_ws, size_t ws_size,
                              hipStream_t stream) {
    const int*   Z      = (const int*)d_in[0];
    const int*   eidx   = (const int*)d_in[1];
    const float* ediff  = (const float*)d_in[2];
    const float* edist  = (const float*)d_in[3];
    const float* emb    = (const float*)d_in[4];
    const float* msg_w1 = (const float*)d_in[5];
    const float* msg_b1 = (const float*)d_in[6];
    const float* msg_w2 = (const float*)d_in[7];
    const float* msg_b2 = (const float*)d_in[8];
    const float* filt_w = (const float*)d_in[9];
    const float* filt_b = (const float*)d_in[10];
    const float* upd_U  = (const float*)d_in[11];
    const float* upd_V  = (const float*)d_in[12];
    const float* upd_w1 = (const float*)d_in[13];
    const float* upd_b1 = (const float*)d_in[14];
    const float* upd_w2 = (const float*)d_in[15];
    const float* upd_b2 = (const float*)d_in[16];
    const float* ro_w1  = (const float*)d_in[17];
    const float* ro_b1  = (const float*)d_in[18];
    const float* ro_w2  = (const float*)d_in[19];
    const float* ro_b2  = (const float*)d_in[20];
    float* out = (float*)d_out;

    // ---------------- workspace layout ----------------
    float* ws = (float*)d_ws;
    float* s   = ws;                      // N*F f32
    float* v   = s + N_ATOMS * F;         // N*3F f32
    float* roT = v + N_ATOMS * 3 * F;     // 64*F f32
    int* count  = (int*)(roT + 64 * F);   // N
    int* bucket = count + N_ATOMS;        // N*CAP
    EMeta* meta = (EMeta*)(bucket + N_ATOMS * CAP);           // N*CAP*32B
    _Float16* rbfh = (_Float16*)(meta + N_ATOMS * CAP);       // N*CAP*24
    _Float16* s_h    = rbfh + (size_t)N_ATOMS * CAP * 24;     // N*F
    _Float16* v_h    = s_h + (size_t)N_ATOMS * F;             // N*3F
    _Float16* vmid_h = v_h + (size_t)N_ATOMS * 3 * F;         // N*3F
    _Float16* phi_h  = vmid_h + (size_t)N_ATOMS * 3 * F;      // N*3F
    _Float16* wh     = phi_h + (size_t)N_ATOMS * 3 * F;       // f16 weights

    const int HWL = 16384 + 49152 + 32768 + 32768 + 49152 + 384 * 24;  // +fwT
    _Float16* mw1T = wh;                   // [128][128]
    _Float16* mw2T = wh + 16384;           // [384][128]
    _Float16* uvT  = wh + 65536;           // [256][128]
    _Float16* uw1T = wh + 98304;           // [128][256]
    _Float16* uw2T = wh + 131072;          // [384][128]
    _Float16* fwTl = wh + 180224;          // [384][24]

    // ---------------- transpose plan ----------------
    TPlansX P; int nb = 0, pi = 0;
    auto add = [&](const float* src, void* dst, int R, int C, int isf16, int pad) {
        P.p[pi].src = src; P.p[pi].dst = dst; P.p[pi].R = R; P.p[pi].C = C;
        P.p[pi].blk0 = nb; P.p[pi].isf16 = isf16; P.p[pi].pad = pad;
        nb += (R * C + 255) / 256; ++pi;
    };
    for (int l = 0; l < NL; ++l) {
        add(msg_w1 + l * F * F,     mw1T + (size_t)l * HWL, F, F, 1, F);
        add(msg_w2 + l * F * 3 * F, mw2T + (size_t)l * HWL, F, 3 * F, 1, F);
        add(upd_U  + l * F * F,     uvT  + (size_t)l * HWL, F, F, 1, F);
        add(upd_V  + l * F * F,     uvT  + (size_t)l * HWL + F * F, F, F, 1, F);
        add(upd_w1 + l * 2 * F * F, uw1T + (size_t)l * HWL, 2 * F, F, 1, 2 * F);
        add(upd_w2 + l * F * 3 * F, uw2T + (size_t)l * HWL, F, 3 * F, 1, F);
        add(filt_w + l * B * 3 * F, fwTl + (size_t)l * HWL, B, 3 * F, 1, 24);
    }
    add(ro_w1, roT, F, 64, 0, F);
    P.n = pi;

    // ---------------- launch ----------------
    init_kernel<<<N_ATOMS, F, 0, stream>>>(Z, emb, s, s_h, v, v_h, count);
    fill_buckets<<<(N_EDGES + 255) / 256, 256, 0, stream>>>(eidx, count, bucket);
    transpose_x<<<nb, 256, 0, stream>>>(P);
    edge_meta_kernel<<<(N_ATOMS * CAP + 255) / 256, 256, 0, stream>>>(
        count, bucket, eidx, ediff, edist, meta, rbfh);

    const int GB = (N_ATOMS + 15) / 16;   // 313
    phi_mlp_kernel<<<GB, 256, 0, stream>>>(
        s_h, mw1T, msg_b1, mw2T, msg_b2, phi_h);
    for (int l = 0; l < NL; ++l) {
        edge_agg_kernel<<<N_ATOMS, 256, 0, stream>>>(
            count, meta, rbfh, fwTl + (size_t)l * HWL, filt_b + l * 3 * F,
            phi_h, v_h, s, v, vmid_h);
        int do_phi = (l + 1 < NL);
        int ln = do_phi ? (l + 1) : l;   // dummy valid ptrs when not used
        fused_update_kernel<<<GB, 256, 0, stream>>>(
            vmid_h, uvT + (size_t)l * HWL,
            uw1T + (size_t)l * HWL, upd_b1 + l * F,
            uw2T + (size_t)l * HWL, upd_b2 + l * 3 * F,
            s, v, s_h, v_h,
            mw1T + (size_t)ln * HWL, msg_b1 + ln * F,
            mw2T + (size_t)ln * HWL, msg_b2 + ln * 3 * F,
            phi_h, do_phi);
    }
    readout_kernel<<<GB, 64, 0, stream>>>(s, roT, ro_b1, ro_w2, ro_b2, out);
}

// Round 12
// 377.831 us; speedup vs baseline: 2.3793x; 1.0227x over previous
//
#include <hip/hip_runtime.h>
#include <hip/hip_bf16.h>
#include <hip/hip_fp16.h>
#include <math.h>

#define N_ATOMS 5000
#define N_EDGES 100000
#define F 128
#define B 20
#define NL 3
#define CAP 64

constexpr float CUTOFF = 5.0f;
constexpr float PI_F = 3.14159265358979323846f;

typedef _Float16 f16x8 __attribute__((ext_vector_type(8)));
typedef _Float16 h2 __attribute__((ext_vector_type(2)));
typedef float f32x4 __attribute__((ext_vector_type(4)));

struct EMeta { int src; float env; float u0, u1, u2; int pad[3]; };  // 32 B

__device__ __forceinline__ float silu_f(float x) { return x / (1.0f + __expf(-x)); }

// pv layout: per (atom, t): [phi0, phi1, phi2, v0, v1, v2, 0, 0] f16 (16 B)
#define PV_IDX(atom, t) (((size_t)(atom) * F + (t)) * 8)

// ---------------------------------------------------------------- init
__global__ void init_kernel(const int* __restrict__ Z, const float* __restrict__ emb,
                            float* __restrict__ s, _Float16* __restrict__ s_h,
                            float* __restrict__ v, _Float16* __restrict__ pv,
                            int* __restrict__ count) {
    int atom = blockIdx.x;
    int t = threadIdx.x;
    float val = emb[Z[atom] * F + t];
    s[atom * F + t] = val;
    s_h[atom * F + t] = (_Float16)val;
#pragma unroll
    for (int d = 0; d < 3; ++d) v[(size_t)atom * 3 * F + d * F + t] = 0.0f;
    f16x8 z = {};
    *(f16x8*)(pv + PV_IDX(atom, t)) = z;
    if (t == 0) count[atom] = 0;
}

// ---------------------------------------------------------------- bucket edges by dst
__global__ void fill_buckets(const int* __restrict__ eidx, int* __restrict__ count,
                             int* __restrict__ bucket) {
    int e = blockIdx.x * 256 + threadIdx.x;
    if (e >= N_EDGES) return;
    int dst = eidx[2 * e];
    int pos = atomicAdd(&count[dst], 1);
    if (pos < CAP) bucket[dst * CAP + pos] = e;
}

// ---------------------------------------------------------------- per-slot edge metadata
__global__ void edge_meta_kernel(const int* __restrict__ count, const int* __restrict__ bucket,
                                 const int* __restrict__ eidx, const float* __restrict__ ediff,
                                 const float* __restrict__ edist,
                                 EMeta* __restrict__ meta, _Float16* __restrict__ rbfh) {
    int slot = blockIdx.x * 256 + threadIdx.x;
    if (slot >= N_ATOMS * CAP) return;
    int a = slot / CAP, i = slot % CAP;
    if (i >= count[a]) return;
    int e = bucket[slot];
    float d = edist[e];
    EMeta m;
    m.src = eidx[2 * e + 1];
    float fc = 0.5f * (cosf(PI_F * d / CUTOFF) + 1.0f);
    m.env = (d < CUTOFF) ? fc : 0.0f;
    float inv = 1.0f / d;
    m.u0 = ediff[3 * e + 0] * inv;
    m.u1 = ediff[3 * e + 1] * inv;
    m.u2 = ediff[3 * e + 2] * inv;
    m.pad[0] = m.pad[1] = m.pad[2] = 0;
    meta[slot] = m;
    _Float16* rp = rbfh + (size_t)slot * 24;
#pragma unroll
    for (int b = 0; b < B; ++b)
        rp[b] = (_Float16)(sinf(d * (float)(b + 1) * (PI_F / CUTOFF)) / d);
    rp[20] = rp[21] = rp[22] = rp[23] = (_Float16)0.0f;
}

// ---------------------------------------------------------------- transpose (f16/f32, padded rows)
struct TPlanX { const float* src; void* dst; int R, C, blk0, isf16, pad; };
struct TPlansX { TPlanX p[24]; int n; };

__global__ void transpose_x(TPlansX P) {
    int b = blockIdx.x;
    int pi = 0;
#pragma unroll
    for (int i = 1; i < 24; ++i)
        if (i < P.n && b >= P.p[i].blk0) pi = i;
    const float* src = P.p[pi].src;
    int R = P.p[pi].R, C = P.p[pi].C, pad = P.p[pi].pad;
    int f = (b - P.p[pi].blk0) * 256 + threadIdx.x;
    if (f < R * C) {
        int c = f / R, r = f - c * R;
        float val = src[r * C + c];
        if (P.p[pi].isf16) ((_Float16*)P.p[pi].dst)[c * pad + r] = (_Float16)val;
        else ((float*)P.p[pi].dst)[c * pad + r] = val;
    }
}

// ---------------------------------------------------------------- phiMLP (layer 0 only) -> pv phi slots
__global__ __launch_bounds__(256) void phi_mlp_kernel(
    const _Float16* __restrict__ s_h, const _Float16* __restrict__ w1T,
    const float* __restrict__ b1, const _Float16* __restrict__ w2T,
    const float* __restrict__ b2, _Float16* __restrict__ pv) {
    __shared__ __align__(16) _Float16 shA[16 * 136];
    __shared__ __align__(16) _Float16 shH[16 * 136];
    int r0 = blockIdx.x * 16;
    int tid = threadIdx.x;
    {
        int r = tid >> 4, c8 = (tid & 15) * 8;
        int rg = r0 + r; if (rg >= N_ATOMS) rg = N_ATOMS - 1;
        *(f16x8*)(shA + r * 136 + c8) = *(const f16x8*)(s_h + (size_t)rg * F + c8);
    }
    __syncthreads();
    int lane = tid & 63, wv = tid >> 6;
    int col = lane & 15, quad = lane >> 4;
    for (int nt = wv; nt < 8; nt += 4) {
        int n = nt * 16 + col;
        f32x4 acc = {0.f, 0.f, 0.f, 0.f};
#pragma unroll
        for (int kt = 0; kt < 4; ++kt) {
            f16x8 afr = *(const f16x8*)(shA + col * 136 + kt * 32 + quad * 8);
            f16x8 bfr = *(const f16x8*)(w1T + (size_t)n * 128 + kt * 32 + quad * 8);
            acc = __builtin_amdgcn_mfma_f32_16x16x32_f16(afr, bfr, acc, 0, 0, 0);
        }
        float bb = b1[n];
#pragma unroll
        for (int r = 0; r < 4; ++r)
            shH[(quad * 4 + r) * 136 + n] = (_Float16)silu_f(acc[r] + bb);
    }
    __syncthreads();
    for (int nt = wv; nt < 24; nt += 4) {
        int n = nt * 16 + col;
        f32x4 acc = {0.f, 0.f, 0.f, 0.f};
#pragma unroll
        for (int kt = 0; kt < 4; ++kt) {
            f16x8 afr = *(const f16x8*)(shH + col * 136 + kt * 32 + quad * 8);
            f16x8 bfr = *(const f16x8*)(w2T + (size_t)n * 128 + kt * 32 + quad * 8);
            acc = __builtin_amdgcn_mfma_f32_16x16x32_f16(afr, bfr, acc, 0, 0, 0);
        }
        float bb = b2[n];
#pragma unroll
        for (int r = 0; r < 4; ++r) {
            int row = r0 + quad * 4 + r;
            if (row < N_ATOMS)
                pv[PV_IDX(row, n & 127) + (n >> 7)] = (_Float16)(acc[r] + bb);
        }
    }
}

// ---------------------------------------------------------------- per-dst edge aggregation
// single 16B pv gather per edge per thread; filter via fdot2.
__global__ __launch_bounds__(256) void edge_agg_kernel(
    const int* __restrict__ count, const EMeta* __restrict__ meta,
    const _Float16* __restrict__ rbfh,
    const _Float16* __restrict__ fwT,   // [384][24] f16
    const float* __restrict__ fb,
    const _Float16* __restrict__ pv,
    float* __restrict__ s, float* __restrict__ v,
    _Float16* __restrict__ vmid_h) {
    int a = blockIdx.x;
    int tid = threadIdx.x;
    int t = tid & 127;
    int team = tid >> 7;

    unsigned int rw0[10], rw1[10], rw2[10];
    {
        const unsigned int* p0 = (const unsigned int*)(fwT + (size_t)t * 24);
        const unsigned int* p1 = (const unsigned int*)(fwT + (size_t)(F + t) * 24);
        const unsigned int* p2 = (const unsigned int*)(fwT + (size_t)(2 * F + t) * 24);
#pragma unroll
        for (int j = 0; j < 10; ++j) { rw0[j] = p0[j]; rw1[j] = p1[j]; rw2[j] = p2[j]; }
    }
    float fb0 = fb[t], fb1 = fb[F + t], fb2 = fb[2 * F + t];

    int n = count[a]; if (n > CAP) n = CAP;
    float accS = 0.f, accV0 = 0.f, accV1 = 0.f, accV2 = 0.f;

    __shared__ int sh_src[32];
    __shared__ float sh_env[32];
    __shared__ float sh_unit[32][3];
    __shared__ __align__(16) unsigned int sh_rbf[32 * 12];
    __shared__ __align__(16) float sh_part[4][F];
    const size_t aC = (size_t)a * CAP;
    const unsigned int* rbf32 = (const unsigned int*)rbfh;

    for (int base = 0; base < n; base += 32) {
        int cnt = min(32, n - base);
        __syncthreads();
        if (tid < cnt) {
            EMeta m = meta[aC + base + tid];
            sh_src[tid] = m.src;
            sh_env[tid] = m.env;
            sh_unit[tid][0] = m.u0; sh_unit[tid][1] = m.u1; sh_unit[tid][2] = m.u2;
        }
        for (int task = tid; task < cnt * 12; task += 256) {
            int i = task / 12, w = task - i * 12;
            sh_rbf[i * 12 + w] = rbf32[(aC + base + i) * 12 + w];
        }
        __syncthreads();

        int myCnt = (cnt > team) ? ((cnt - team + 1) >> 1) : 0;
        if (myCnt > 0) {
            f16x8 QA[4], QB[4];
            int ngrp = (myCnt + 3) >> 2;

            auto load_grp = [&](int gbase, f16x8 Q[4]) {
#pragma unroll
                for (int j = 0; j < 4; ++j) {
                    int i = gbase + j;
                    int ii = (i < myCnt) ? i : (myCnt - 1);
                    int src = sh_src[team + 2 * ii];
                    Q[j] = *(const f16x8*)(pv + PV_IDX(src, t));
                }
            };
            auto comp_grp = [&](int gbase, f16x8 Q[4]) {
#pragma unroll
                for (int j = 0; j < 4; ++j) {
                    int i = gbase + j;
                    if (i < myCnt) {
                        int ei = team + 2 * i;
                        const uint4* rq = (const uint4*)(sh_rbf + ei * 12);
                        uint4 qa = rq[0], qb = rq[1];
                        uint2 qc = *(const uint2*)(sh_rbf + ei * 12 + 8);
                        unsigned int rr[10] = {qa.x, qa.y, qa.z, qa.w,
                                               qb.x, qb.y, qb.z, qb.w, qc.x, qc.y};
                        float f0 = fb0, f1 = fb1, f2 = fb2;
#pragma unroll
                        for (int p = 0; p < 10; ++p) {
                            h2 rb = __builtin_bit_cast(h2, rr[p]);
                            f0 = __builtin_amdgcn_fdot2(rb, __builtin_bit_cast(h2, rw0[p]), f0, false);
                            f1 = __builtin_amdgcn_fdot2(rb, __builtin_bit_cast(h2, rw1[p]), f1, false);
                            f2 = __builtin_amdgcn_fdot2(rb, __builtin_bit_cast(h2, rw2[p]), f2, false);
                        }
                        float env = sh_env[ei];
                        f0 *= env; f1 *= env; f2 *= env;
                        accS += f2 * (float)Q[j][2];
                        float gsv = f0 * (float)Q[j][0];
                        float gev = f1 * (float)Q[j][1];
                        accV0 += (float)Q[j][3] * gsv + gev * sh_unit[ei][0];
                        accV1 += (float)Q[j][4] * gsv + gev * sh_unit[ei][1];
                        accV2 += (float)Q[j][5] * gsv + gev * sh_unit[ei][2];
                    }
                }
            };

            load_grp(0, QA);
            for (int g = 0; g < ngrp; g += 2) {
                if (g + 1 < ngrp) load_grp((g + 1) * 4, QB);
                comp_grp(g * 4, QA);
                if (g + 1 < ngrp) {
                    if (g + 2 < ngrp) load_grp((g + 2) * 4, QA);
                    comp_grp((g + 1) * 4, QB);
                }
            }
        }
    }

    __syncthreads();
    if (team == 1) {
        sh_part[0][t] = accS; sh_part[1][t] = accV0;
        sh_part[2][t] = accV1; sh_part[3][t] = accV2;
    }
    __syncthreads();
    if (team == 0) {
        float sm = s[a * F + t] + accS + sh_part[0][t];
        s[a * F + t] = sm;
        float vm0 = v[a * 3 * F + t] + accV0 + sh_part[1][t];
        float vm1 = v[a * 3 * F + F + t] + accV1 + sh_part[2][t];
        float vm2 = v[a * 3 * F + 2 * F + t] + accV2 + sh_part[3][t];
        v[a * 3 * F + t] = vm0;
        v[a * 3 * F + F + t] = vm1;
        v[a * 3 * F + 2 * F + t] = vm2;
        vmid_h[(size_t)(a * 3 + 0) * F + t] = (_Float16)vm0;
        vmid_h[(size_t)(a * 3 + 1) * F + t] = (_Float16)vm1;
        vmid_h[(size_t)(a * 3 + 2) * F + t] = (_Float16)vm2;
    }
}

// ---------------------------------------------------------------- fused update (+ next phi OR readout)
__global__ __launch_bounds__(256) void fused_update_kernel(
    const _Float16* __restrict__ vmid_h, const _Float16* __restrict__ uvT,
    const _Float16* __restrict__ w1T, const float* __restrict__ b1,
    const _Float16* __restrict__ w2T, const float* __restrict__ b2,
    float* __restrict__ s, float* __restrict__ v, _Float16* __restrict__ pv,
    const _Float16* __restrict__ nw1T, const float* __restrict__ nb1,
    const _Float16* __restrict__ nw2T, const float* __restrict__ nb2,
    int do_phi,
    const _Float16* __restrict__ roT16, const float* __restrict__ rb1,
    const float* __restrict__ rw2, const float* __restrict__ rb2,
    float* __restrict__ out, int do_ro) {
    __shared__ __align__(16) _Float16 shA[48 * 136];    // vmid tile; reused as s-tile
    __shared__ __align__(16) _Float16 shUV[48 * 264];
    __shared__ __align__(16) _Float16 shCat[16 * 264];
    __shared__ __align__(16) _Float16 shH[16 * 136];
    __shared__ __align__(16) _Float16 shAa[16 * 392];
    _Float16* shS = shA;
    float* shRO = (float*)shAa;   // 16 x 68 f32
    int a0 = blockIdx.x * 16;
    int r0 = a0 * 3;
    int tid = threadIdx.x;
    for (int slot = tid; slot < 48 * 16; slot += 256) {
        int r = slot >> 4, c8 = (slot & 15) * 8;
        int rg = r0 + r; if (rg >= N_ATOMS * 3) rg = N_ATOMS * 3 - 1;
        *(f16x8*)(shA + r * 136 + c8) = *(const f16x8*)(vmid_h + (size_t)rg * F + c8);
    }
    __syncthreads();
    int lane = tid & 63, wv = tid >> 6;
    int col = lane & 15, quad = lane >> 4;

    // stage 1: UV = vmid @ [U|V]
    for (int j = wv; j < 48; j += 4) {
        int mt = j >> 4, nt = j & 15;
        int n = nt * 16 + col;
        f32x4 acc = {0.f, 0.f, 0.f, 0.f};
#pragma unroll
        for (int kt = 0; kt < 4; ++kt) {
            f16x8 afr = *(const f16x8*)(shA + (mt * 16 + col) * 136 + kt * 32 + quad * 8);
            f16x8 bfr = *(const f16x8*)(uvT + (size_t)n * 128 + kt * 32 + quad * 8);
            acc = __builtin_amdgcn_mfma_f32_16x16x32_f16(afr, bfr, acc, 0, 0, 0);
        }
#pragma unroll
        for (int r = 0; r < 4; ++r)
            shUV[(mt * 16 + quad * 4 + r) * 264 + n] = (_Float16)acc[r];
    }
    __syncthreads();

    // stage 2: concat = [s, Vn]
    for (int p = tid; p < 2048; p += 256) {
        int ai = p >> 7, t = p & 127;
        int atom = a0 + ai;
        int ag = (atom < N_ATOMS) ? atom : N_ATOMS - 1;
        shCat[ai * 264 + t] = (_Float16)s[(size_t)ag * F + t];
        float x0 = (float)shUV[(ai * 3 + 0) * 264 + 128 + t];
        float x1 = (float)shUV[(ai * 3 + 1) * 264 + 128 + t];
        float x2 = (float)shUV[(ai * 3 + 2) * 264 + 128 + t];
        shCat[ai * 264 + 128 + t] = (_Float16)sqrtf(x0 * x0 + x1 * x1 + x2 * x2);
    }
    __syncthreads();

    // stage 3: hidden = silu(concat @ w1 + b1), K=256
    for (int nt = wv; nt < 8; nt += 4) {
        int n = nt * 16 + col;
        f32x4 acc = {0.f, 0.f, 0.f, 0.f};
#pragma unroll
        for (int kt = 0; kt < 8; ++kt) {
            f16x8 afr = *(const f16x8*)(shCat + col * 264 + kt * 32 + quad * 8);
            f16x8 bfr = *(const f16x8*)(w1T + (size_t)n * 256 + kt * 32 + quad * 8);
            acc = __builtin_amdgcn_mfma_f32_16x16x32_f16(afr, bfr, acc, 0, 0, 0);
        }
        float bb = b1[n];
#pragma unroll
        for (int r = 0; r < 4; ++r)
            shH[(quad * 4 + r) * 136 + n] = (_Float16)silu_f(acc[r] + bb);
    }
    __syncthreads();

    // stage 4: a = hidden @ w2 + b2
    for (int nt = wv; nt < 24; nt += 4) {
        int n = nt * 16 + col;
        f32x4 acc = {0.f, 0.f, 0.f, 0.f};
#pragma unroll
        for (int kt = 0; kt < 4; ++kt) {
            f16x8 afr = *(const f16x8*)(shH + col * 136 + kt * 32 + quad * 8);
            f16x8 bfr = *(const f16x8*)(w2T + (size_t)n * 128 + kt * 32 + quad * 8);
            acc = __builtin_amdgcn_mfma_f32_16x16x32_f16(afr, bfr, acc, 0, 0, 0);
        }
        float bb = b2[n];
#pragma unroll
        for (int r = 0; r < 4; ++r)
            shAa[(quad * 4 + r) * 392 + n] = (_Float16)(acc[r] + bb);
    }
    __syncthreads();

    // stage 5: final elementwise update; new s into shS (f16), new v into pv[3..5]
    for (int p = tid; p < 2048; p += 256) {
        int ai = p >> 7, t = p & 127;
        int atom = a0 + ai;
        if (atom >= N_ATOMS) { shS[ai * 136 + t] = (_Float16)0.0f; continue; }
        float avv = (float)shAa[ai * 392 + t];
        float asv = (float)shAa[ai * 392 + 128 + t];
        float ass = (float)shAa[ai * 392 + 256 + t];
        float dot = 0.f;
        _Float16* pvp = pv + PV_IDX(atom, t);
#pragma unroll
        for (int d = 0; d < 3; ++d) {
            float u = (float)shUV[(ai * 3 + d) * 264 + t];
            float w = (float)shUV[(ai * 3 + d) * 264 + 128 + t];
            dot += u * w;
            float nv = v[(size_t)atom * 3 * F + d * F + t] + avv * u;
            v[(size_t)atom * 3 * F + d * F + t] = nv;
            pvp[3 + d] = (_Float16)nv;
        }
        float sn = s[(size_t)atom * F + t] + asv * dot + ass;
        s[(size_t)atom * F + t] = sn;
        shS[ai * 136 + t] = (_Float16)sn;
    }

    // stage 6a: next layer's phi -> pv[0..2]
    if (do_phi) {
        __syncthreads();
        for (int nt = wv; nt < 8; nt += 4) {
            int n = nt * 16 + col;
            f32x4 acc = {0.f, 0.f, 0.f, 0.f};
#pragma unroll
            for (int kt = 0; kt < 4; ++kt) {
                f16x8 afr = *(const f16x8*)(shS + col * 136 + kt * 32 + quad * 8);
                f16x8 bfr = *(const f16x8*)(nw1T + (size_t)n * 128 + kt * 32 + quad * 8);
                acc = __builtin_amdgcn_mfma_f32_16x16x32_f16(afr, bfr, acc, 0, 0, 0);
            }
            float bb = nb1[n];
#pragma unroll
            for (int r = 0; r < 4; ++r)
                shH[(quad * 4 + r) * 136 + n] = (_Float16)silu_f(acc[r] + bb);
        }
        __syncthreads();
        for (int nt = wv; nt < 24; nt += 4) {
            int n = nt * 16 + col;
            f32x4 acc = {0.f, 0.f, 0.f, 0.f};
#pragma unroll
            for (int kt = 0; kt < 4; ++kt) {
                f16x8 afr = *(const f16x8*)(shH + col * 136 + kt * 32 + quad * 8);
                f16x8 bfr = *(const f16x8*)(nw2T + (size_t)n * 128 + kt * 32 + quad * 8);
                acc = __builtin_amdgcn_mfma_f32_16x16x32_f16(afr, bfr, acc, 0, 0, 0);
            }
            float bb = nb2[n];
#pragma unroll
            for (int r = 0; r < 4; ++r) {
                int row = a0 + quad * 4 + r;
                if (row < N_ATOMS)
                    pv[PV_IDX(row, n & 127) + (n >> 7)] = (_Float16)(acc[r] + bb);
            }
        }
    }

    // stage 6b: readout (last layer): out = silu(s_new @ ro_w1 + rb1) @ rw2 + rb2
    if (do_ro) {
        __syncthreads();
        if (wv < 4) {
            int n = wv * 16 + col;   // n in [0,64)
            f32x4 acc = {0.f, 0.f, 0.f, 0.f};
#pragma unroll
            for (int kt = 0; kt < 4; ++kt) {
                f16x8 afr = *(const f16x8*)(shS + col * 136 + kt * 32 + quad * 8);
                f16x8 bfr = *(const f16x8*)(roT16 + (size_t)n * 128 + kt * 32 + quad * 8);
                acc = __builtin_amdgcn_mfma_f32_16x16x32_f16(afr, bfr, acc, 0, 0, 0);
            }
            float bb = rb1[n], w2n = rw2[n];
#pragma unroll
            for (int r = 0; r < 4; ++r)
                shRO[(quad * 4 + r) * 68 + n] = silu_f(acc[r] + bb) * w2n;
        }
        __syncthreads();
        if (tid < 16) {
            int atom = a0 + tid;
            if (atom < N_ATOMS) {
                float sum = rb2[0];
#pragma unroll 8
                for (int k = 0; k < 64; ++k) sum += shRO[tid * 68 + k];
                out[atom] = sum;
            }
        }
    }
}

extern "C" void kernel_launch(void* const* d_in, const int* in_sizes, int n_in,
                              void* d_out, int out_size, void* d_ws, size_t ws_size,
                              hipStream_t stream) {
    const int*   Z      = (const int*)d_in[0];
    const int*   eidx   = (const int*)d_in[1];
    const float* ediff  = (const float*)d_in[2];
    const float* edist  = (const float*)d_in[3];
    const float* emb    = (const float*)d_in[4];
    const float* msg_w1 = (const float*)d_in[5];
    const float* msg_b1 = (const float*)d_in[6];
    const float* msg_w2 = (const float*)d_in[7];
    const float* msg_b2 = (const float*)d_in[8];
    const float* filt_w = (const float*)d_in[9];
    const float* filt_b = (const float*)d_in[10];
    const float* upd_U  = (const float*)d_in[11];
    const float* upd_V  = (const float*)d_in[12];
    const float* upd_w1 = (const float*)d_in[13];
    const float* upd_b1 = (const float*)d_in[14];
    const float* upd_w2 = (const float*)d_in[15];
    const float* upd_b2 = (const float*)d_in[16];
    const float* ro_w1  = (const float*)d_in[17];
    const float* ro_b1  = (const float*)d_in[18];
    const float* ro_w2  = (const float*)d_in[19];
    const float* ro_b2  = (const float*)d_in[20];
    float* out = (float*)d_out;

    // ---------------- workspace layout ----------------
    float* ws = (float*)d_ws;
    float* s   = ws;                      // N*F f32
    float* v   = s + N_ATOMS * F;         // N*3F f32
    int* count  = (int*)(v + N_ATOMS * 3 * F);   // N
    int* bucket = count + N_ATOMS;               // N*CAP
    EMeta* meta = (EMeta*)(bucket + N_ATOMS * CAP);           // N*CAP*32B
    _Float16* rbfh = (_Float16*)(meta + N_ATOMS * CAP);       // N*CAP*24
    _Float16* s_h    = rbfh + (size_t)N_ATOMS * CAP * 24;     // N*F
    _Float16* vmid_h = s_h + (size_t)N_ATOMS * F;             // N*3F
    _Float16* pv     = vmid_h + (size_t)N_ATOMS * 3 * F;      // N*F*8
    _Float16* wh     = pv + (size_t)N_ATOMS * F * 8;          // f16 weights

    const int HWL = 16384 + 49152 + 32768 + 32768 + 49152 + 384 * 24;
    _Float16* mw1T = wh;                   // [128][128]
    _Float16* mw2T = wh + 16384;           // [384][128]
    _Float16* uvT  = wh + 65536;           // [256][128]
    _Float16* uw1T = wh + 98304;           // [128][256]
    _Float16* uw2T = wh + 131072;          // [384][128]
    _Float16* fwTl = wh + 180224;          // [384][24]
    _Float16* roT16 = wh + (size_t)NL * HWL;  // [64][128]

    // ---------------- transpose plan ----------------
    TPlansX P; int nb = 0, pi = 0;
    auto add = [&](const float* src, void* dst, int R, int C, int isf16, int pad) {
        P.p[pi].src = src; P.p[pi].dst = dst; P.p[pi].R = R; P.p[pi].C = C;
        P.p[pi].blk0 = nb; P.p[pi].isf16 = isf16; P.p[pi].pad = pad;
        nb += (R * C + 255) / 256; ++pi;
    };
    for (int l = 0; l < NL; ++l) {
        add(msg_w1 + l * F * F,     mw1T + (size_t)l * HWL, F, F, 1, F);
        add(msg_w2 + l * F * 3 * F, mw2T + (size_t)l * HWL, F, 3 * F, 1, F);
        add(upd_U  + l * F * F,     uvT  + (size_t)l * HWL, F, F, 1, F);
        add(upd_V  + l * F * F,     uvT  + (size_t)l * HWL + F * F, F, F, 1, F);
        add(upd_w1 + l * 2 * F * F, uw1T + (size_t)l * HWL, 2 * F, F, 1, 2 * F);
        add(upd_w2 + l * F * 3 * F, uw2T + (size_t)l * HWL, F, 3 * F, 1, F);
        add(filt_w + l * B * 3 * F, fwTl + (size_t)l * HWL, B, 3 * F, 1, 24);
    }
    add(ro_w1, roT16, F, 64, 1, F);
    P.n = pi;

    // ---------------- launch ----------------
    init_kernel<<<N_ATOMS, F, 0, stream>>>(Z, emb, s, s_h, v, pv, count);
    fill_buckets<<<(N_EDGES + 255) / 256, 256, 0, stream>>>(eidx, count, bucket);
    transpose_x<<<nb, 256, 0, stream>>>(P);
    edge_meta_kernel<<<(N_ATOMS * CAP + 255) / 256, 256, 0, stream>>>(
        count, bucket, eidx, ediff, edist, meta, rbfh);

    const int GB = (N_ATOMS + 15) / 16;   // 313
    phi_mlp_kernel<<<GB, 256, 0, stream>>>(
        s_h, mw1T, msg_b1, mw2T, msg_b2, pv);
    for (int l = 0; l < NL; ++l) {
        edge_agg_kernel<<<N_ATOMS, 256, 0, stream>>>(
            count, meta, rbfh, fwTl + (size_t)l * HWL, filt_b + l * 3 * F,
            pv, s, v, vmid_h);
        int do_phi = (l + 1 < NL);
        int do_ro = (l == NL - 1);
        int ln = do_phi ? (l + 1) : l;
        fused_update_kernel<<<GB, 256, 0, stream>>>(
            vmid_h, uvT + (size_t)l * HWL,
            uw1T + (size_t)l * HWL, upd_b1 + l * F,
            uw2T + (size_t)l * HWL, upd_b2 + l * 3 * F,
            s, v, pv,
            mw1T + (size_t)ln * HWL, msg_b1 + ln * F,
            mw2T + (size_t)ln * HWL, msg_b2 + ln * 3 * F, do_phi,
            roT16, ro_b1, ro_w2, ro_b2, out, do_ro);
    }
}